// Round 1
// baseline (3883.541 us; speedup 1.0000x reference)
//
#include <hip/hip_runtime.h>
#include <hip/hip_bf16.h>

// Problem constants
// x: (2, 3, 192, 192, 180) fp32 ; windows: 1152 of 192 tokens (3x8x8); heads 6 x 30
#define NWIN 1152
#define NTOK 192
#define NQTOK 64
#define CDIM 180
#define NHEAD 6
#define HDIM 30

// Output layout (floats): xo (2*192*192*181) | pred_q (1152*64*180) | x_pred (1152*64*180)
#define XO_ELEMS   13344768
#define PRED_ELEMS 13271040

__device__ inline void load_shift(const int* sp, int& s0, int& s1, int& s2) {
    // Heuristic: harness may deliver shift_size as int32[3] or raw int64[3].
    // int64 little-endian view as int32: odd slots are the high words (=0 for small values).
    int v0 = sp[0], v1 = sp[1], v2 = sp[2], v3 = sp[3], v4 = sp[4], v5 = sp[5];
    if (v1 == 0 && v3 == 0 && v5 == 0) { s0 = v0; s1 = v2; s2 = v4; }
    else { s0 = v0; s1 = v1; s2 = v2; }
    s0 = ((s0 % 3) + 3) % 3;
    s1 = ((s1 % 192) + 192) % 192;
    s2 = ((s2 % 192) + 192) % 192;
}

__device__ inline float dot4(float4 a, float4 b) {
    return a.x * b.x + a.y * b.y + a.z * b.z + a.w * b.w;
}

// ---------------------------------------------------------------------------
// Kernel A: QKV projection over all window tokens (gather from rolled x).
// Tile: 64 window-tokens x 32 n-columns. Thread: 2 tokens x 4 n. K=180 fp32.
// Writes k/v (all 192 tokens) and q (tokens 128..191, pre-scaled) as bf16.
// Also writes pred_q (exact fp32 copy of gathered x for query tokens).
// ---------------------------------------------------------------------------
__global__ __launch_bounds__(256) void kA(
    const float* __restrict__ x, const float* __restrict__ wq, const float* __restrict__ bq,
    const int* __restrict__ shiftp,
    __hip_bfloat16* __restrict__ qb, __hip_bfloat16* __restrict__ kb, __hip_bfloat16* __restrict__ vb,
    float* __restrict__ predq)
{
    __shared__ float xs[64][180];
    __shared__ int rowbase[64];
    int s0, s1, s2; load_shift(shiftp, s0, s1, s2);
    const int tile  = blockIdx.x;   // 3456 token tiles of 64
    const int ntile = blockIdx.y;   // 17 n tiles of 32
    const int tid   = threadIdx.x;
    const int g0    = tile * 64;

    if (tid < 64) {
        int g = g0 + tid;
        int win = g / 192;
        int n = g - win * 192;
        int d = n >> 6;
        int rem = n & 63;
        int i = rem >> 3, j = rem & 7;
        int bb = win / 576;
        int hw = win - bb * 576;
        int hj = hw / 24, wj = hw - hj * 24;
        int t = d + s0; if (t >= 3) t -= 3;
        int ho = hj * 8 + i + s1; if (ho >= 192) ho -= 192;
        int wo = wj * 8 + j + s2; if (wo >= 192) wo -= 192;
        rowbase[tid] = (((bb * 3 + t) * 192 + ho) * 192 + wo) * 180;
    }
    __syncthreads();
    for (int idx = tid; idx < 64 * 180; idx += 256) {
        int r = idx / 180;
        int cc = idx - r * 180;
        xs[r][cc] = x[rowbase[r] + cc];
    }
    __syncthreads();

    // pred_q: exact copy of gathered x for the d==2 slice (one n-tile only)
    if (ntile == 0 && (tile % 3) == 2) {
        for (int idx = tid; idx < 64 * 180; idx += 256) {
            int r = idx / 180;
            int cc = idx - r * 180;
            int g = g0 + r;
            int win = g / 192;
            predq[(win * 64 + r) * 180 + cc] = xs[r][cc]; // local query idx == r (g0 is 64-aligned)
        }
    }

    const int nq = tid & 7;
    const int tp = tid >> 3;
    const int n0 = ntile * 32 + nq * 4;
    if (n0 >= 540) return;
    const int t0 = tp * 2;

    float a00 = 0, a01 = 0, a02 = 0, a03 = 0, a10 = 0, a11 = 0, a12 = 0, a13 = 0;
    for (int k = 0; k < 180; k += 4) {
        float4 w0 = *(const float4*)(wq + (n0 + 0) * 180 + k);
        float4 w1 = *(const float4*)(wq + (n0 + 1) * 180 + k);
        float4 w2 = *(const float4*)(wq + (n0 + 2) * 180 + k);
        float4 w3 = *(const float4*)(wq + (n0 + 3) * 180 + k);
        float4 xa = *(const float4*)(&xs[t0][k]);
        float4 xb = *(const float4*)(&xs[t0 + 1][k]);
        a00 += dot4(w0, xa); a01 += dot4(w1, xa); a02 += dot4(w2, xa); a03 += dot4(w3, xa);
        a10 += dot4(w0, xb); a11 += dot4(w1, xb); a12 += dot4(w2, xb); a13 += dot4(w3, xb);
    }
    float accs[2][4] = {{a00, a01, a02, a03}, {a10, a11, a12, a13}};
    #pragma unroll
    for (int tt = 0; tt < 2; ++tt) {
        int g = g0 + t0 + tt;
        int win = g / 192;
        int ntok = g - win * 192;
        #pragma unroll
        for (int rr = 0; rr < 4; ++rr) {
            int n = n0 + rr;
            float val = accs[tt][rr] + bq[n];
            int which = n / 180;
            int hrem = n - which * 180;
            int head = hrem / 30;
            int dd = hrem - head * 30;
            if (which == 0) {
                if (ntok >= 128)
                    qb[((win * 6 + head) * 64 + (ntok - 128)) * 30 + dd] =
                        __float2bfloat16(val * 0.18257418583505536f); // 30^-0.5
            } else if (which == 1) {
                kb[((win * 6 + head) * 192 + ntok) * 30 + dd] = __float2bfloat16(val);
            } else {
                vb[((win * 6 + head) * 192 + ntok) * 30 + dd] = __float2bfloat16(val);
            }
        }
    }
}

// ---------------------------------------------------------------------------
// Kernel B: attention per (window, head). 256 threads: 64 rows x 4 lanes/row.
// S (64x192) in registers (fully unrolled), bias computed from closed-form
// REL_IDX: (2-dk)*225 + (yi-yk+7)*15 + (xi-xk+7). Softmax via 4-lane shfl_xor.
// ---------------------------------------------------------------------------
__global__ __launch_bounds__(256) void kB(
    const __hip_bfloat16* __restrict__ qb, const __hip_bfloat16* __restrict__ kb,
    const __hip_bfloat16* __restrict__ vb, const float* __restrict__ rpb,
    __hip_bfloat16* __restrict__ ob)
{
    __shared__ float ql[64][30];
    __shared__ float kl[192][30];
    __shared__ float vl[192][30];
    const int blk = blockIdx.x;
    const int win = blk / 6, head = blk - (blk / 6) * 6;
    const int tid = threadIdx.x;
    const __hip_bfloat16* qsrc = qb + (win * 6 + head) * 64 * 30;
    const __hip_bfloat16* ksrc = kb + (win * 6 + head) * 192 * 30;
    const __hip_bfloat16* vsrc = vb + (win * 6 + head) * 192 * 30;
    for (int idx = tid; idx < 64 * 30; idx += 256)  ((float*)ql)[idx] = __bfloat162float(qsrc[idx]);
    for (int idx = tid; idx < 192 * 30; idx += 256) ((float*)kl)[idx] = __bfloat162float(ksrc[idx]);
    for (int idx = tid; idx < 192 * 30; idx += 256) ((float*)vl)[idx] = __bfloat162float(vsrc[idx]);
    __syncthreads();

    const int r = tid >> 2, c0 = tid & 3;
    const int yi = r >> 3, xi = r & 7;

    float qr[30];
    #pragma unroll
    for (int d2 = 0; d2 < 15; ++d2) {
        float2 v = *(const float2*)(&ql[r][d2 * 2]);
        qr[2 * d2] = v.x; qr[2 * d2 + 1] = v.y;
    }

    float s[48];
    float m = -1e30f;
    #pragma unroll
    for (int jj = 0; jj < 48; ++jj) {
        int kc = c0 + jj * 4;
        float acc = 0.0f;
        #pragma unroll
        for (int d2 = 0; d2 < 15; ++d2) {
            float2 kv = *(const float2*)(&kl[kc][d2 * 2]);
            acc += qr[2 * d2] * kv.x + qr[2 * d2 + 1] * kv.y;
        }
        int dk = kc >> 6;
        int rm = kc & 63;
        int yk = rm >> 3, xk = rm & 7;
        int ridx = (2 - dk) * 225 + (yi - yk + 7) * 15 + (xi - xk + 7);
        acc += rpb[ridx * 6 + head];
        s[jj] = acc;
        m = fmaxf(m, acc);
    }
    m = fmaxf(m, __shfl_xor(m, 1));
    m = fmaxf(m, __shfl_xor(m, 2));
    float denom = 0.0f;
    #pragma unroll
    for (int jj = 0; jj < 48; ++jj) { s[jj] = __expf(s[jj] - m); denom += s[jj]; }
    denom += __shfl_xor(denom, 1);
    denom += __shfl_xor(denom, 2);
    const float inv = 1.0f / denom;

    float acc[30];
    #pragma unroll
    for (int dd = 0; dd < 30; ++dd) acc[dd] = 0.0f;
    #pragma unroll
    for (int jj = 0; jj < 48; ++jj) {
        int kc = c0 + jj * 4;
        float p = s[jj];
        #pragma unroll
        for (int d2 = 0; d2 < 15; ++d2) {
            float2 vv = *(const float2*)(&vl[kc][d2 * 2]);
            acc[2 * d2] += p * vv.x;
            acc[2 * d2 + 1] += p * vv.y;
        }
    }
    #pragma unroll
    for (int dd = 0; dd < 30; ++dd) {
        acc[dd] += __shfl_xor(acc[dd], 1);
        acc[dd] += __shfl_xor(acc[dd], 2);
    }
    if (c0 == 0) {
        __hip_bfloat16* dst = ob + ((win * 64 + r) * 6 + head) * 30; // [win][qi][head][dd]
        #pragma unroll
        for (int dd = 0; dd < 30; ++dd) dst[dd] = __float2bfloat16(acc[dd] * inv);
    }
}

// ---------------------------------------------------------------------------
// Kernel C: output projection + scatter. Block: one window (64 rows) x 32 cols.
// Writes x_pred and xo (un-window + roll-back; channel 180 = 1.0).
// ---------------------------------------------------------------------------
__global__ __launch_bounds__(256) void kC(
    const __hip_bfloat16* __restrict__ ob, const float* __restrict__ wp, const float* __restrict__ bp,
    const int* __restrict__ shiftp, float* __restrict__ xo, float* __restrict__ xpred)
{
    __shared__ float xs[64][180];
    int s0, s1, s2; load_shift(shiftp, s0, s1, s2);
    const int win   = blockIdx.x;  // 1152
    const int ctile = blockIdx.y;  // 6 tiles of 32 cols
    const int tid   = threadIdx.x;
    const __hip_bfloat16* src = ob + win * 64 * 180;
    for (int idx = tid; idx < 64 * 180; idx += 256)
        ((float*)xs)[idx] = __bfloat162float(src[idx]);
    __syncthreads();

    const int nq = tid & 7;
    const int tp = tid >> 3;
    const int t0 = tp * 2;
    const int c0 = ctile * 32 + nq * 4;
    const int bb = win / 576;
    const int hw = win - bb * 576;
    const int hj = hw / 24, wj = hw - hj * 24;
    if (c0 >= 180) return;

    float a00 = 0, a01 = 0, a02 = 0, a03 = 0, a10 = 0, a11 = 0, a12 = 0, a13 = 0;
    for (int k = 0; k < 180; k += 4) {
        float4 w0 = *(const float4*)(wp + (c0 + 0) * 180 + k);
        float4 w1 = *(const float4*)(wp + (c0 + 1) * 180 + k);
        float4 w2 = *(const float4*)(wp + (c0 + 2) * 180 + k);
        float4 w3 = *(const float4*)(wp + (c0 + 3) * 180 + k);
        float4 xa = *(const float4*)(&xs[t0][k]);
        float4 xb = *(const float4*)(&xs[t0 + 1][k]);
        a00 += dot4(w0, xa); a01 += dot4(w1, xa); a02 += dot4(w2, xa); a03 += dot4(w3, xa);
        a10 += dot4(w0, xb); a11 += dot4(w1, xb); a12 += dot4(w2, xb); a13 += dot4(w3, xb);
    }
    float accs[2][4] = {{a00, a01, a02, a03}, {a10, a11, a12, a13}};
    #pragma unroll
    for (int tt = 0; tt < 2; ++tt) {
        int qi = t0 + tt;
        int i = qi >> 3, j = qi & 7;
        int ho = hj * 8 + i + s1; if (ho >= 192) ho -= 192;
        int wo = wj * 8 + j + s2; if (wo >= 192) wo -= 192;
        float* xrow = xo + ((bb * 192 + ho) * 192 + wo) * 181;
        float* prow = xpred + (win * 64 + qi) * 180;
        #pragma unroll
        for (int rr = 0; rr < 4; ++rr) {
            float val = accs[tt][rr] + bp[c0 + rr];
            xrow[c0 + rr] = val;
            prow[c0 + rr] = val;
        }
        if (ctile == 0 && nq == 0) xrow[180] = 1.0f;
    }
}

// ---------------------------------------------------------------------------
extern "C" void kernel_launch(void* const* d_in, const int* in_sizes, int n_in,
                              void* d_out, int out_size, void* d_ws, size_t ws_size,
                              hipStream_t stream) {
    const float* x      = (const float*)d_in[0];
    const float* w_qkv  = (const float*)d_in[1];
    const float* b_qkv  = (const float*)d_in[2];
    const float* w_proj = (const float*)d_in[3];
    const float* b_proj = (const float*)d_in[4];
    const float* rpb    = (const float*)d_in[5];
    const int*   shiftp = (const int*)d_in[6];

    float* out    = (float*)d_out;
    float* xo     = out;
    float* pred_q = out + XO_ELEMS;
    float* x_pred = out + XO_ELEMS + PRED_ELEMS;

    // workspace (bf16): q [1152][6][64][30], k/v [1152][6][192][30], o [1152][64][180]
    char* ws = (char*)d_ws;
    __hip_bfloat16* qb = (__hip_bfloat16*)(ws);
    __hip_bfloat16* kb = (__hip_bfloat16*)(ws + 26542080);
    __hip_bfloat16* vb = (__hip_bfloat16*)(ws + 26542080 + 79626240);
    __hip_bfloat16* ob = (__hip_bfloat16*)(ws + 26542080 + 79626240 + 79626240);
    // total ws use: 212,336,640 bytes

    dim3 gA(3456, 17);
    hipLaunchKernelGGL(kA, gA, dim3(256), 0, stream, x, w_qkv, b_qkv, shiftp, qb, kb, vb, pred_q);

    hipLaunchKernelGGL(kB, dim3(NWIN * NHEAD), dim3(256), 0, stream, qb, kb, vb, rpb, ob);

    dim3 gC(NWIN, 6);
    hipLaunchKernelGGL(kC, gC, dim3(256), 0, stream, ob, w_proj, b_proj, shiftp, xo, x_pred);
}

// Round 2
// 677.695 us; speedup vs baseline: 5.7305x; 5.7305x over previous
//
#include <hip/hip_runtime.h>
#include <hip/hip_bf16.h>

// x: (2, 3, 192, 192, 180) fp32 ; windows: 1152 of 192 tokens (3x8x8); heads 6 x 30
#define NWIN 1152

// Output layout (floats): xo (2*192*192*181) | pred_q (1152*64*180) | x_pred (1152*64*180)
#define XO_ELEMS   13344768
#define PRED_ELEMS 13271040

typedef __attribute__((ext_vector_type(8))) short short8v;
typedef __attribute__((ext_vector_type(4))) float f32x4;

__device__ inline short bfbits(float f) {
    __hip_bfloat16 h = __float2bfloat16(f);
    return *reinterpret_cast<short*>(&h);
}

__device__ inline void load_shift(const int* sp, int& s0, int& s1, int& s2) {
    // shift_size may arrive as int32[3] or raw int64[3] (odd slots = high words).
    int v0 = sp[0], v1 = sp[1], v2 = sp[2], v3 = sp[3], v4 = sp[4], v5 = sp[5];
    if (v1 == 0 && v3 == 0 && v5 == 0) { s0 = v0; s1 = v2; s2 = v4; }
    else { s0 = v0; s1 = v1; s2 = v2; }
    s0 = ((s0 % 3) + 3) % 3;
    s1 = ((s1 % 192) + 192) % 192;
    s2 = ((s2 % 192) + 192) % 192;
}

// ---------------------------------------------------------------------------
// kW: one-shot weight conversion to padded bf16.
// Wb  [576][192]: rows n<540, cols k<180 from w_qkv, else 0.
// Wpb [192][192]: rows n<180, cols k<180 from w_proj, else 0.
// ---------------------------------------------------------------------------
__global__ __launch_bounds__(256) void kW(const float* __restrict__ wq,
                                          const float* __restrict__ wp,
                                          short* __restrict__ Wb, short* __restrict__ Wpb) {
    int idx = blockIdx.x * 256 + threadIdx.x;
    if (idx < 576 * 192) {
        int n = idx / 192, k = idx - n * 192;
        Wb[idx] = (n < 540 && k < 180) ? bfbits(wq[n * 180 + k]) : (short)0;
    } else {
        idx -= 576 * 192;
        if (idx < 192 * 192) {
            int n = idx / 192, k = idx - n * 192;
            Wpb[idx] = (n < 180 && k < 180) ? bfbits(wp[n * 180 + k]) : (short)0;
        }
    }
}

// ---------------------------------------------------------------------------
// kA: QKV projection via MFMA. One block = 64 tokens (one third of a window)
// x all 540 cols (9 subtiles of 64). 4 waves, each 32x32 via 2x2 fragments of
// mfma_f32_16x16x32_bf16, K = 180 padded to 192. Writes q (scaled, tokens
// 128..191), k, v as bf16; pred_q as exact fp32 during staging.
// ---------------------------------------------------------------------------
__global__ __launch_bounds__(256) void kA(
    const float* __restrict__ x, const short* __restrict__ Wb, const float* __restrict__ bq,
    const int* __restrict__ shiftp,
    short* __restrict__ qb, short* __restrict__ kb, short* __restrict__ vb,
    float* __restrict__ predq)
{
    __shared__ short As[64 * 200];   // [tok][k], row stride 200 (pad 8)
    __shared__ short Ws[64 * 200];   // [n][k]
    __shared__ int rowbase[64];
    int s0, s1, s2; load_shift(shiftp, s0, s1, s2);
    const int tile = blockIdx.x;          // 3456
    const int tid  = threadIdx.x;
    const int g0   = tile * 64;
    const int win  = tile / 3;
    const int ntokbase = (tile - win * 3) * 64;
    const bool isq = (ntokbase == 128);

    if (tid < 64) {
        int g = g0 + tid;
        int n = g - win * 192;
        int d = n >> 6;
        int rem = n & 63;
        int i = rem >> 3, j = rem & 7;
        int bb = win / 576;
        int hw = win - bb * 576;
        int hj = hw / 24, wj = hw - hj * 24;
        int t = d + s0; if (t >= 3) t -= 3;
        int ho = hj * 8 + i + s1; if (ho >= 192) ho -= 192;
        int wo = wj * 8 + j + s2; if (wo >= 192) wo -= 192;
        rowbase[tid] = (((bb * 3 + t) * 192 + ho) * 192 + wo) * 180;
    }
    __syncthreads();
    // stage A: fp32 -> bf16 (and exact fp32 pred_q for the query tile)
    for (int idx = tid; idx < 64 * 45; idx += 256) {
        int r = idx / 45, c4 = idx - r * 45;
        float4 v = *(const float4*)(x + rowbase[r] + c4 * 4);
        if (isq) *(float4*)(predq + (win * 64 + r) * 180 + c4 * 4) = v;
        short4 s = make_short4(bfbits(v.x), bfbits(v.y), bfbits(v.z), bfbits(v.w));
        *(short4*)(&As[r * 200 + c4 * 4]) = s;
    }
    if (tid < 192) {  // zero k-pad [180..191] : 64 rows x 3 chunks of 4 shorts
        int r = tid / 3, p = tid - r * 3;
        *(short4*)(&As[r * 200 + 180 + p * 4]) = make_short4(0, 0, 0, 0);
    }

    const int l  = tid & 63;
    const int w  = tid >> 6;
    const int wm = w >> 1, wn = w & 1;
    const int lr = l & 15, lg = l >> 4;

    for (int ns = 0; ns < 9; ++ns) {
        __syncthreads();
        for (int idx = tid; idx < 1536; idx += 256) {  // 64 rows x 24 short8
            int r = idx / 24, c8 = idx - r * 24;
            *(short8v*)(&Ws[r * 200 + c8 * 8]) = *(const short8v*)(Wb + (ns * 64 + r) * 192 + c8 * 8);
        }
        __syncthreads();
        f32x4 acc[2][2];
        #pragma unroll
        for (int i = 0; i < 2; ++i)
            #pragma unroll
            for (int j = 0; j < 2; ++j) acc[i][j] = (f32x4){0.f, 0.f, 0.f, 0.f};
        #pragma unroll
        for (int kk = 0; kk < 6; ++kk) {
            int k0 = kk * 32 + lg * 8;
            short8v a0 = *(const short8v*)(&As[(wm * 32 + lr) * 200 + k0]);
            short8v a1 = *(const short8v*)(&As[(wm * 32 + 16 + lr) * 200 + k0]);
            short8v b0 = *(const short8v*)(&Ws[(wn * 32 + lr) * 200 + k0]);
            short8v b1 = *(const short8v*)(&Ws[(wn * 32 + 16 + lr) * 200 + k0]);
            acc[0][0] = __builtin_amdgcn_mfma_f32_16x16x32_bf16(a0, b0, acc[0][0], 0, 0, 0);
            acc[0][1] = __builtin_amdgcn_mfma_f32_16x16x32_bf16(a0, b1, acc[0][1], 0, 0, 0);
            acc[1][0] = __builtin_amdgcn_mfma_f32_16x16x32_bf16(a1, b0, acc[1][0], 0, 0, 0);
            acc[1][1] = __builtin_amdgcn_mfma_f32_16x16x32_bf16(a1, b1, acc[1][1], 0, 0, 0);
        }
        #pragma unroll
        for (int bf = 0; bf < 2; ++bf) {
            int n = ns * 64 + wn * 32 + bf * 16 + lr;
            if (n >= 540) continue;
            float bias = bq[n];
            int which = n / 180;
            int hrem = n - which * 180;
            int head = hrem / 30;
            int dd = hrem - head * 30;
            #pragma unroll
            for (int af = 0; af < 2; ++af) {
                #pragma unroll
                for (int r = 0; r < 4; ++r) {
                    int ntok = ntokbase + wm * 32 + af * 16 + lg * 4 + r;
                    float val = acc[af][bf][r] + bias;
                    if (which == 0) {
                        if (ntok >= 128)
                            qb[((win * 6 + head) * 64 + (ntok - 128)) * 30 + dd] =
                                bfbits(val * 0.18257418583505536f);  // 30^-0.5
                    } else if (which == 1) {
                        kb[((win * 6 + head) * 192 + ntok) * 30 + dd] = bfbits(val);
                    } else {
                        vb[((win * 6 + head) * 192 + ntok) * 30 + dd] = bfbits(val);
                    }
                }
            }
        }
    }
}

// ---------------------------------------------------------------------------
// kB: attention per (window, head) — unchanged from round 1.
// ---------------------------------------------------------------------------
__global__ __launch_bounds__(256) void kB(
    const __hip_bfloat16* __restrict__ qb, const __hip_bfloat16* __restrict__ kb,
    const __hip_bfloat16* __restrict__ vb, const float* __restrict__ rpb,
    __hip_bfloat16* __restrict__ ob)
{
    __shared__ float ql[64][30];
    __shared__ float kl[192][30];
    __shared__ float vl[192][30];
    const int blk = blockIdx.x;
    const int win = blk / 6, head = blk - (blk / 6) * 6;
    const int tid = threadIdx.x;
    const __hip_bfloat16* qsrc = qb + (win * 6 + head) * 64 * 30;
    const __hip_bfloat16* ksrc = kb + (win * 6 + head) * 192 * 30;
    const __hip_bfloat16* vsrc = vb + (win * 6 + head) * 192 * 30;
    for (int idx = tid; idx < 64 * 30; idx += 256)  ((float*)ql)[idx] = __bfloat162float(qsrc[idx]);
    for (int idx = tid; idx < 192 * 30; idx += 256) ((float*)kl)[idx] = __bfloat162float(ksrc[idx]);
    for (int idx = tid; idx < 192 * 30; idx += 256) ((float*)vl)[idx] = __bfloat162float(vsrc[idx]);
    __syncthreads();

    const int r = tid >> 2, c0 = tid & 3;
    const int yi = r >> 3, xi = r & 7;

    float qr[30];
    #pragma unroll
    for (int d2 = 0; d2 < 15; ++d2) {
        float2 v = *(const float2*)(&ql[r][d2 * 2]);
        qr[2 * d2] = v.x; qr[2 * d2 + 1] = v.y;
    }

    float s[48];
    float m = -1e30f;
    #pragma unroll
    for (int jj = 0; jj < 48; ++jj) {
        int kc = c0 + jj * 4;
        float acc = 0.0f;
        #pragma unroll
        for (int d2 = 0; d2 < 15; ++d2) {
            float2 kv = *(const float2*)(&kl[kc][d2 * 2]);
            acc += qr[2 * d2] * kv.x + qr[2 * d2 + 1] * kv.y;
        }
        int dk = kc >> 6;
        int rm = kc & 63;
        int yk = rm >> 3, xk = rm & 7;
        int ridx = (2 - dk) * 225 + (yi - yk + 7) * 15 + (xi - xk + 7);
        acc += rpb[ridx * 6 + head];
        s[jj] = acc;
        m = fmaxf(m, acc);
    }
    m = fmaxf(m, __shfl_xor(m, 1));
    m = fmaxf(m, __shfl_xor(m, 2));
    float denom = 0.0f;
    #pragma unroll
    for (int jj = 0; jj < 48; ++jj) { s[jj] = __expf(s[jj] - m); denom += s[jj]; }
    denom += __shfl_xor(denom, 1);
    denom += __shfl_xor(denom, 2);
    const float inv = 1.0f / denom;

    float acc[30];
    #pragma unroll
    for (int dd = 0; dd < 30; ++dd) acc[dd] = 0.0f;
    #pragma unroll
    for (int jj = 0; jj < 48; ++jj) {
        int kc = c0 + jj * 4;
        float p = s[jj];
        #pragma unroll
        for (int d2 = 0; d2 < 15; ++d2) {
            float2 vv = *(const float2*)(&vl[kc][d2 * 2]);
            acc[2 * d2] += p * vv.x;
            acc[2 * d2 + 1] += p * vv.y;
        }
    }
    #pragma unroll
    for (int dd = 0; dd < 30; ++dd) {
        acc[dd] += __shfl_xor(acc[dd], 1);
        acc[dd] += __shfl_xor(acc[dd], 2);
    }
    if (c0 == 0) {
        __hip_bfloat16* dst = ob + ((win * 64 + r) * 6 + head) * 30; // [win][qi][head*30+dd]
        #pragma unroll
        for (int dd = 0; dd < 30; ++dd) dst[dd] = __float2bfloat16(acc[dd] * inv);
    }
}

// ---------------------------------------------------------------------------
// kC: output projection via MFMA + scatter. One block = one window (64 rows),
// 3 N-subtiles of 64 (valid < 180). Same fragment machinery as kA.
// ---------------------------------------------------------------------------
__global__ __launch_bounds__(256) void kC(
    const short* __restrict__ ob, const short* __restrict__ Wpb, const float* __restrict__ bp,
    const int* __restrict__ shiftp, float* __restrict__ xo, float* __restrict__ xpred)
{
    __shared__ short As[64 * 200];
    __shared__ short Ws[64 * 200];
    int s0, s1, s2; load_shift(shiftp, s0, s1, s2);
    const int win = blockIdx.x;   // 1152
    const int tid = threadIdx.x;
    const int bb = win / 576;
    const int hw = win - bb * 576;
    const int hj = hw / 24, wj = hw - hj * 24;

    const short* src = ob + win * 64 * 180;
    for (int idx = tid; idx < 64 * 45; idx += 256) {
        int r = idx / 45, c4 = idx - r * 45;
        *(short4*)(&As[r * 200 + c4 * 4]) = *(const short4*)(src + r * 180 + c4 * 4);
    }
    if (tid < 192) {
        int r = tid / 3, p = tid - r * 3;
        *(short4*)(&As[r * 200 + 180 + p * 4]) = make_short4(0, 0, 0, 0);
    }

    const int l  = tid & 63;
    const int w  = tid >> 6;
    const int wm = w >> 1, wn = w & 1;
    const int lr = l & 15, lg = l >> 4;

    for (int ns = 0; ns < 3; ++ns) {
        __syncthreads();
        for (int idx = tid; idx < 1536; idx += 256) {
            int r = idx / 24, c8 = idx - r * 24;
            *(short8v*)(&Ws[r * 200 + c8 * 8]) = *(const short8v*)(Wpb + (ns * 64 + r) * 192 + c8 * 8);
        }
        __syncthreads();
        f32x4 acc[2][2];
        #pragma unroll
        for (int i = 0; i < 2; ++i)
            #pragma unroll
            for (int j = 0; j < 2; ++j) acc[i][j] = (f32x4){0.f, 0.f, 0.f, 0.f};
        #pragma unroll
        for (int kk = 0; kk < 6; ++kk) {
            int k0 = kk * 32 + lg * 8;
            short8v a0 = *(const short8v*)(&As[(wm * 32 + lr) * 200 + k0]);
            short8v a1 = *(const short8v*)(&As[(wm * 32 + 16 + lr) * 200 + k0]);
            short8v b0 = *(const short8v*)(&Ws[(wn * 32 + lr) * 200 + k0]);
            short8v b1 = *(const short8v*)(&Ws[(wn * 32 + 16 + lr) * 200 + k0]);
            acc[0][0] = __builtin_amdgcn_mfma_f32_16x16x32_bf16(a0, b0, acc[0][0], 0, 0, 0);
            acc[0][1] = __builtin_amdgcn_mfma_f32_16x16x32_bf16(a0, b1, acc[0][1], 0, 0, 0);
            acc[1][0] = __builtin_amdgcn_mfma_f32_16x16x32_bf16(a1, b0, acc[1][0], 0, 0, 0);
            acc[1][1] = __builtin_amdgcn_mfma_f32_16x16x32_bf16(a1, b1, acc[1][1], 0, 0, 0);
        }
        #pragma unroll
        for (int af = 0; af < 2; ++af) {
            #pragma unroll
            for (int r = 0; r < 4; ++r) {
                int qi = wm * 32 + af * 16 + lg * 4 + r;
                int i = qi >> 3, j = qi & 7;
                int ho = hj * 8 + i + s1; if (ho >= 192) ho -= 192;
                int wo = wj * 8 + j + s2; if (wo >= 192) wo -= 192;
                float* xrow = xo + ((bb * 192 + ho) * 192 + wo) * 181;
                float* prow = xpred + (win * 64 + qi) * 180;
                #pragma unroll
                for (int bf = 0; bf < 2; ++bf) {
                    int n = ns * 64 + wn * 32 + bf * 16 + lr;
                    if (n < 180) {
                        float val = acc[af][bf][r] + bp[n];
                        xrow[n] = val;
                        prow[n] = val;
                    }
                }
                if (ns == 0 && wn == 0 && lr == 0) xrow[180] = 1.0f;
            }
        }
    }
}

// ---------------------------------------------------------------------------
extern "C" void kernel_launch(void* const* d_in, const int* in_sizes, int n_in,
                              void* d_out, int out_size, void* d_ws, size_t ws_size,
                              hipStream_t stream) {
    const float* x      = (const float*)d_in[0];
    const float* w_qkv  = (const float*)d_in[1];
    const float* b_qkv  = (const float*)d_in[2];
    const float* w_proj = (const float*)d_in[3];
    const float* b_proj = (const float*)d_in[4];
    const float* rpb    = (const float*)d_in[5];
    const int*   shiftp = (const int*)d_in[6];

    float* out    = (float*)d_out;
    float* xo     = out;
    float* pred_q = out + XO_ELEMS;
    float* x_pred = out + XO_ELEMS + PRED_ELEMS;

    // ws layout (bytes):
    // Wb 221184 | Wpb 73728 | qb 26542080 | kb 79626240 | vb 79626240 | ob 26542080
    char* ws = (char*)d_ws;
    short* Wb  = (short*)(ws);
    short* Wpb = (short*)(ws + 221184);
    short* qb  = (short*)(ws + 294912);
    short* kb  = (short*)(ws + 294912 + 26542080);
    short* vb  = (short*)(ws + 294912 + 26542080 + 79626240);
    short* ob  = (short*)(ws + 294912 + 26542080 + 79626240 + 79626240);
    // total: 212,631,552 bytes

    hipLaunchKernelGGL(kW, dim3(576), dim3(256), 0, stream, w_qkv, w_proj, Wb, Wpb);
    hipLaunchKernelGGL(kA, dim3(3456), dim3(256), 0, stream, x, Wb, b_qkv, shiftp, qb, kb, vb, pred_q);
    hipLaunchKernelGGL(kB, dim3(NWIN * 6), dim3(256), 0, stream,
                       (const __hip_bfloat16*)qb, (const __hip_bfloat16*)kb,
                       (const __hip_bfloat16*)vb, rpb, (__hip_bfloat16*)ob);
    hipLaunchKernelGGL(kC, dim3(NWIN), dim3(256), 0, stream, ob, Wpb, b_proj, shiftp, xo, x_pred);
}

// Round 4
// 464.559 us; speedup vs baseline: 8.3596x; 1.4588x over previous
//
#include <hip/hip_runtime.h>
#include <hip/hip_bf16.h>

// x: (2, 3, 192, 192, 180) fp32 ; windows: 1152 of 192 tokens (3x8x8); heads 6 x 30
#define NWIN 1152

// Output layout (floats): xo (2*192*192*181) | pred_q (1152*64*180) | x_pred (1152*64*180)
#define XO_ELEMS   13344768
#define PRED_ELEMS 13271040

typedef __attribute__((ext_vector_type(8))) short short8v;
typedef __attribute__((ext_vector_type(4))) float f32x4;

__device__ inline short bfbits(float f) {
    __hip_bfloat16 h = __float2bfloat16(f);
    return *reinterpret_cast<short*>(&h);
}

__device__ inline void load_shift(const int* sp, int& s0, int& s1, int& s2) {
    // shift_size may arrive as int32[3] or raw int64[3] (odd slots = high words).
    int v0 = sp[0], v1 = sp[1], v2 = sp[2], v3 = sp[3], v4 = sp[4], v5 = sp[5];
    if (v1 == 0 && v3 == 0 && v5 == 0) { s0 = v0; s1 = v2; s2 = v4; }
    else { s0 = v0; s1 = v1; s2 = v2; }
    s0 = ((s0 % 3) + 3) % 3;
    s1 = ((s1 % 192) + 192) % 192;
    s2 = ((s2 % 192) + 192) % 192;
}

// ---------------------------------------------------------------------------
// kW: one-shot weight conversion to padded bf16.
// ---------------------------------------------------------------------------
__global__ __launch_bounds__(256) void kW(const float* __restrict__ wq,
                                          const float* __restrict__ wp,
                                          short* __restrict__ Wb, short* __restrict__ Wpb) {
    int idx = blockIdx.x * 256 + threadIdx.x;
    if (idx < 576 * 192) {
        int n = idx / 192, k = idx - n * 192;
        Wb[idx] = (n < 540 && k < 180) ? bfbits(wq[n * 180 + k]) : (short)0;
    } else {
        idx -= 576 * 192;
        if (idx < 192 * 192) {
            int n = idx / 192, k = idx - n * 192;
            Wpb[idx] = (n < 180 && k < 180) ? bfbits(wp[n * 180 + k]) : (short)0;
        }
    }
}

// ---------------------------------------------------------------------------
// kA: QKV projection via MFMA (unchanged, verified round 2).
// ---------------------------------------------------------------------------
__global__ __launch_bounds__(256) void kA(
    const float* __restrict__ x, const short* __restrict__ Wb, const float* __restrict__ bq,
    const int* __restrict__ shiftp,
    short* __restrict__ qb, short* __restrict__ kb, short* __restrict__ vb,
    float* __restrict__ predq)
{
    __shared__ short As[64 * 200];
    __shared__ short Ws[64 * 200];
    __shared__ int rowbase[64];
    int s0, s1, s2; load_shift(shiftp, s0, s1, s2);
    const int tile = blockIdx.x;          // 3456
    const int tid  = threadIdx.x;
    const int g0   = tile * 64;
    const int win  = tile / 3;
    const int ntokbase = (tile - win * 3) * 64;
    const bool isq = (ntokbase == 128);

    if (tid < 64) {
        int g = g0 + tid;
        int n = g - win * 192;
        int d = n >> 6;
        int rem = n & 63;
        int i = rem >> 3, j = rem & 7;
        int bb = win / 576;
        int hw = win - bb * 576;
        int hj = hw / 24, wj = hw - hj * 24;
        int t = d + s0; if (t >= 3) t -= 3;
        int ho = hj * 8 + i + s1; if (ho >= 192) ho -= 192;
        int wo = wj * 8 + j + s2; if (wo >= 192) wo -= 192;
        rowbase[tid] = (((bb * 3 + t) * 192 + ho) * 192 + wo) * 180;
    }
    __syncthreads();
    for (int idx = tid; idx < 64 * 45; idx += 256) {
        int r = idx / 45, c4 = idx - r * 45;
        float4 v = *(const float4*)(x + rowbase[r] + c4 * 4);
        if (isq) *(float4*)(predq + (win * 64 + r) * 180 + c4 * 4) = v;
        short4 s = make_short4(bfbits(v.x), bfbits(v.y), bfbits(v.z), bfbits(v.w));
        *(short4*)(&As[r * 200 + c4 * 4]) = s;
    }
    if (tid < 192) {
        int r = tid / 3, p = tid - r * 3;
        *(short4*)(&As[r * 200 + 180 + p * 4]) = make_short4(0, 0, 0, 0);
    }

    const int l  = tid & 63;
    const int w  = tid >> 6;
    const int wm = w >> 1, wn = w & 1;
    const int lr = l & 15, lg = l >> 4;

    for (int ns = 0; ns < 9; ++ns) {
        __syncthreads();
        for (int idx = tid; idx < 1536; idx += 256) {
            int r = idx / 24, c8 = idx - r * 24;
            *(short8v*)(&Ws[r * 200 + c8 * 8]) = *(const short8v*)(Wb + (ns * 64 + r) * 192 + c8 * 8);
        }
        __syncthreads();
        f32x4 acc[2][2];
        #pragma unroll
        for (int i = 0; i < 2; ++i)
            #pragma unroll
            for (int j = 0; j < 2; ++j) acc[i][j] = (f32x4){0.f, 0.f, 0.f, 0.f};
        #pragma unroll
        for (int kk = 0; kk < 6; ++kk) {
            int k0 = kk * 32 + lg * 8;
            short8v a0 = *(const short8v*)(&As[(wm * 32 + lr) * 200 + k0]);
            short8v a1 = *(const short8v*)(&As[(wm * 32 + 16 + lr) * 200 + k0]);
            short8v b0 = *(const short8v*)(&Ws[(wn * 32 + lr) * 200 + k0]);
            short8v b1 = *(const short8v*)(&Ws[(wn * 32 + 16 + lr) * 200 + k0]);
            acc[0][0] = __builtin_amdgcn_mfma_f32_16x16x32_bf16(a0, b0, acc[0][0], 0, 0, 0);
            acc[0][1] = __builtin_amdgcn_mfma_f32_16x16x32_bf16(a0, b1, acc[0][1], 0, 0, 0);
            acc[1][0] = __builtin_amdgcn_mfma_f32_16x16x32_bf16(a1, b0, acc[1][0], 0, 0, 0);
            acc[1][1] = __builtin_amdgcn_mfma_f32_16x16x32_bf16(a1, b1, acc[1][1], 0, 0, 0);
        }
        #pragma unroll
        for (int bf = 0; bf < 2; ++bf) {
            int n = ns * 64 + wn * 32 + bf * 16 + lr;
            if (n >= 540) continue;
            float bias = bq[n];
            int which = n / 180;
            int hrem = n - which * 180;
            int head = hrem / 30;
            int dd = hrem - head * 30;
            #pragma unroll
            for (int af = 0; af < 2; ++af) {
                #pragma unroll
                for (int r = 0; r < 4; ++r) {
                    int ntok = ntokbase + wm * 32 + af * 16 + lg * 4 + r;
                    float val = acc[af][bf][r] + bias;
                    if (which == 0) {
                        if (ntok >= 128)
                            qb[((win * 6 + head) * 64 + (ntok - 128)) * 30 + dd] =
                                bfbits(val * 0.18257418583505536f);  // 30^-0.5
                    } else if (which == 1) {
                        kb[((win * 6 + head) * 192 + ntok) * 30 + dd] = bfbits(val);
                    } else {
                        vb[((win * 6 + head) * 192 + ntok) * 30 + dd] = bfbits(val);
                    }
                }
            }
        }
    }
}

// ---------------------------------------------------------------------------
// kB: MFMA attention. One block = (window, head), 4 waves x 16 q-rows.
// FIX vs round 3: K/V staging loops cover all 2880 ints (was 1440 — half of
// Kl/Vt was uninitialized garbage -> NaN). Vt pad rows 30/31 zeroed.
// ---------------------------------------------------------------------------
__global__ __launch_bounds__(256) void kB(
    const short* __restrict__ qb, const short* __restrict__ kb,
    const short* __restrict__ vb, const float* __restrict__ rpb,
    short* __restrict__ ob)
{
    __shared__ __attribute__((aligned(16))) short Ql[64 * 40];   // [qi][k], stride 40
    __shared__ __attribute__((aligned(16))) short Kl[192 * 40];  // [kc][k]
    __shared__ __attribute__((aligned(16))) short Vt[32 * 200];  // [dd][kc], stride 200
    __shared__ __attribute__((aligned(16))) short Pl[64 * 200];  // [qi][kc]
    __shared__ float rpbl[675];
    const int blk = blockIdx.x;
    const int win = blk / 6, head = blk - win * 6;
    const int tid = threadIdx.x;

    const short* qsrc = qb + (win * 6 + head) * 64 * 30;
    const short* ksrc = kb + (win * 6 + head) * 192 * 30;
    const short* vsrc = vb + (win * 6 + head) * 192 * 30;

    // stage Q (1920 shorts = 960 ints), unpack stride-30 -> stride-40
    for (int i = tid; i < 960; i += 256) {
        int v = ((const int*)qsrc)[i];
        int f = 2 * i;
        int t = f / 30, d = f - t * 30;   // d is always even (f even)
        Ql[t * 40 + d] = (short)(v & 0xffff);
        Ql[t * 40 + d + 1] = (short)((unsigned)v >> 16);
    }
    // stage K (5760 shorts = 2880 ints)
    for (int i = tid; i < 2880; i += 256) {
        int v = ((const int*)ksrc)[i];
        int f = 2 * i;
        int t = f / 30, d = f - t * 30;
        Kl[t * 40 + d] = (short)(v & 0xffff);
        Kl[t * 40 + d + 1] = (short)((unsigned)v >> 16);
    }
    // stage V transposed: Vt[dd][tok] (5760 shorts = 2880 ints)
    for (int i = tid; i < 2880; i += 256) {
        int v = ((const int*)vsrc)[i];
        int f = 2 * i;
        int t = f / 30, d = f - t * 30;
        Vt[d * 200 + t] = (short)(v & 0xffff);
        Vt[(d + 1) * 200 + t] = (short)((unsigned)v >> 16);
    }
    // zero k-pads (Ql/Kl k=30,31) and Vt pad rows (dd=30,31)
    if (tid < 64)  *(int*)(&Ql[tid * 40 + 30]) = 0;
    if (tid < 192) *(int*)(&Kl[tid * 40 + 30]) = 0;
    if (tid < 50)  *(short8v*)(&Vt[30 * 200 + tid * 8]) = (short8v){0,0,0,0,0,0,0,0};
    // rpb column for this head
    for (int i = tid; i < 675; i += 256) rpbl[i] = rpb[i * 6 + head];
    __syncthreads();

    const int l  = tid & 63;
    const int w  = tid >> 6;
    const int lr = l & 15, lg = l >> 4;
    const int rowbase = w * 16;

    // ---- QK^T ----
    short8v aq = *(const short8v*)(&Ql[(rowbase + lr) * 40 + lg * 8]);
    f32x4 s[12];
    #pragma unroll
    for (int f = 0; f < 12; ++f) {
        short8v b = *(const short8v*)(&Kl[(f * 16 + lr) * 40 + lg * 8]);
        s[f] = __builtin_amdgcn_mfma_f32_16x16x32_bf16(aq, b, (f32x4){0.f, 0.f, 0.f, 0.f}, 0, 0, 0);
    }

    // ---- bias + softmax ----
    int cr[4];
    #pragma unroll
    for (int r = 0; r < 4; ++r) {
        int qi = rowbase + lg * 4 + r;
        int yi = qi >> 3, xi = qi & 7;
        cr[r] = yi * 15 + xi + 112;  // +7*15+7
    }
    #pragma unroll
    for (int f = 0; f < 12; ++f) {
        int kc = f * 16 + lr;
        int dk = kc >> 6;
        int rm = kc & 63;
        int yk = rm >> 3, xk = rm & 7;
        int koff = (2 - dk) * 225 - yk * 15 - xk;
        #pragma unroll
        for (int r = 0; r < 4; ++r) s[f][r] += rpbl[cr[r] + koff];
    }
    float m0 = s[0][0], m1 = s[0][1], m2 = s[0][2], m3 = s[0][3];
    #pragma unroll
    for (int f = 1; f < 12; ++f) {
        m0 = fmaxf(m0, s[f][0]); m1 = fmaxf(m1, s[f][1]);
        m2 = fmaxf(m2, s[f][2]); m3 = fmaxf(m3, s[f][3]);
    }
    #pragma unroll
    for (int d = 1; d < 16; d <<= 1) {
        m0 = fmaxf(m0, __shfl_xor(m0, d)); m1 = fmaxf(m1, __shfl_xor(m1, d));
        m2 = fmaxf(m2, __shfl_xor(m2, d)); m3 = fmaxf(m3, __shfl_xor(m3, d));
    }
    float d0 = 0.f, d1 = 0.f, d2 = 0.f, d3 = 0.f;
    #pragma unroll
    for (int f = 0; f < 12; ++f) {
        float p0 = __expf(s[f][0] - m0); d0 += p0;
        float p1 = __expf(s[f][1] - m1); d1 += p1;
        float p2 = __expf(s[f][2] - m2); d2 += p2;
        float p3 = __expf(s[f][3] - m3); d3 += p3;
        int col = f * 16 + lr;
        Pl[(rowbase + lg * 4 + 0) * 200 + col] = bfbits(p0);
        Pl[(rowbase + lg * 4 + 1) * 200 + col] = bfbits(p1);
        Pl[(rowbase + lg * 4 + 2) * 200 + col] = bfbits(p2);
        Pl[(rowbase + lg * 4 + 3) * 200 + col] = bfbits(p3);
    }
    #pragma unroll
    for (int d = 1; d < 16; d <<= 1) {
        d0 += __shfl_xor(d0, d); d1 += __shfl_xor(d1, d);
        d2 += __shfl_xor(d2, d); d3 += __shfl_xor(d3, d);
    }
    float inv[4] = {1.f / d0, 1.f / d1, 1.f / d2, 1.f / d3};

    // ---- PV ---- (wave reads only its own P rows: in-order LDS within wave)
    f32x4 o0 = (f32x4){0.f, 0.f, 0.f, 0.f};
    f32x4 o1 = (f32x4){0.f, 0.f, 0.f, 0.f};
    #pragma unroll
    for (int ks = 0; ks < 6; ++ks) {
        int k0 = ks * 32 + lg * 8;
        short8v pa = *(const short8v*)(&Pl[(rowbase + lr) * 200 + k0]);
        short8v b0 = *(const short8v*)(&Vt[lr * 200 + k0]);
        short8v b1 = *(const short8v*)(&Vt[(16 + lr) * 200 + k0]);
        o0 = __builtin_amdgcn_mfma_f32_16x16x32_bf16(pa, b0, o0, 0, 0, 0);
        o1 = __builtin_amdgcn_mfma_f32_16x16x32_bf16(pa, b1, o1, 0, 0, 0);
    }
    #pragma unroll
    for (int r = 0; r < 4; ++r) {
        int qi = rowbase + lg * 4 + r;
        short* dst = ob + ((win * 64 + qi) * 6 + head) * 30;
        dst[lr] = bfbits(o0[r] * inv[r]);                    // dd = 0..15
        if (lr < 14) dst[16 + lr] = bfbits(o1[r] * inv[r]);  // dd = 16..29
    }
}

// ---------------------------------------------------------------------------
// kC: output projection via MFMA + scatter (unchanged, verified round 2).
// ---------------------------------------------------------------------------
__global__ __launch_bounds__(256) void kC(
    const short* __restrict__ ob, const short* __restrict__ Wpb, const float* __restrict__ bp,
    const int* __restrict__ shiftp, float* __restrict__ xo, float* __restrict__ xpred)
{
    __shared__ short As[64 * 200];
    __shared__ short Ws[64 * 200];
    int s0, s1, s2; load_shift(shiftp, s0, s1, s2);
    const int win = blockIdx.x;
    const int tid = threadIdx.x;
    const int bb = win / 576;
    const int hw = win - bb * 576;
    const int hj = hw / 24, wj = hw - hj * 24;

    const short* src = ob + win * 64 * 180;
    for (int idx = tid; idx < 64 * 45; idx += 256) {
        int r = idx / 45, c4 = idx - r * 45;
        *(short4*)(&As[r * 200 + c4 * 4]) = *(const short4*)(src + r * 180 + c4 * 4);
    }
    if (tid < 192) {
        int r = tid / 3, p = tid - r * 3;
        *(short4*)(&As[r * 200 + 180 + p * 4]) = make_short4(0, 0, 0, 0);
    }

    const int l  = tid & 63;
    const int w  = tid >> 6;
    const int wm = w >> 1, wn = w & 1;
    const int lr = l & 15, lg = l >> 4;

    for (int ns = 0; ns < 3; ++ns) {
        __syncthreads();
        for (int idx = tid; idx < 1536; idx += 256) {
            int r = idx / 24, c8 = idx - r * 24;
            *(short8v*)(&Ws[r * 200 + c8 * 8]) = *(const short8v*)(Wpb + (ns * 64 + r) * 192 + c8 * 8);
        }
        __syncthreads();
        f32x4 acc[2][2];
        #pragma unroll
        for (int i = 0; i < 2; ++i)
            #pragma unroll
            for (int j = 0; j < 2; ++j) acc[i][j] = (f32x4){0.f, 0.f, 0.f, 0.f};
        #pragma unroll
        for (int kk = 0; kk < 6; ++kk) {
            int k0 = kk * 32 + lg * 8;
            short8v a0 = *(const short8v*)(&As[(wm * 32 + lr) * 200 + k0]);
            short8v a1 = *(const short8v*)(&As[(wm * 32 + 16 + lr) * 200 + k0]);
            short8v b0 = *(const short8v*)(&Ws[(wn * 32 + lr) * 200 + k0]);
            short8v b1 = *(const short8v*)(&Ws[(wn * 32 + 16 + lr) * 200 + k0]);
            acc[0][0] = __builtin_amdgcn_mfma_f32_16x16x32_bf16(a0, b0, acc[0][0], 0, 0, 0);
            acc[0][1] = __builtin_amdgcn_mfma_f32_16x16x32_bf16(a0, b1, acc[0][1], 0, 0, 0);
            acc[1][0] = __builtin_amdgcn_mfma_f32_16x16x32_bf16(a1, b0, acc[1][0], 0, 0, 0);
            acc[1][1] = __builtin_amdgcn_mfma_f32_16x16x32_bf16(a1, b1, acc[1][1], 0, 0, 0);
        }
        #pragma unroll
        for (int af = 0; af < 2; ++af) {
            #pragma unroll
            for (int r = 0; r < 4; ++r) {
                int qi = wm * 32 + af * 16 + lg * 4 + r;
                int i = qi >> 3, j = qi & 7;
                int ho = hj * 8 + i + s1; if (ho >= 192) ho -= 192;
                int wo = wj * 8 + j + s2; if (wo >= 192) wo -= 192;
                float* xrow = xo + ((bb * 192 + ho) * 192 + wo) * 181;
                float* prow = xpred + (win * 64 + qi) * 180;
                #pragma unroll
                for (int bf = 0; bf < 2; ++bf) {
                    int n = ns * 64 + wn * 32 + bf * 16 + lr;
                    if (n < 180) {
                        float val = acc[af][bf][r] + bp[n];
                        xrow[n] = val;
                        prow[n] = val;
                    }
                }
                if (ns == 0 && wn == 0 && lr == 0) xrow[180] = 1.0f;
            }
        }
    }
}

// ---------------------------------------------------------------------------
extern "C" void kernel_launch(void* const* d_in, const int* in_sizes, int n_in,
                              void* d_out, int out_size, void* d_ws, size_t ws_size,
                              hipStream_t stream) {
    const float* x      = (const float*)d_in[0];
    const float* w_qkv  = (const float*)d_in[1];
    const float* b_qkv  = (const float*)d_in[2];
    const float* w_proj = (const float*)d_in[3];
    const float* b_proj = (const float*)d_in[4];
    const float* rpb    = (const float*)d_in[5];
    const int*   shiftp = (const int*)d_in[6];

    float* out    = (float*)d_out;
    float* xo     = out;
    float* pred_q = out + XO_ELEMS;
    float* x_pred = out + XO_ELEMS + PRED_ELEMS;

    // ws layout (bytes): Wb 221184 | Wpb 73728 | qb 26542080 | kb 79626240 | vb 79626240 | ob 26542080
    char* ws = (char*)d_ws;
    short* Wb  = (short*)(ws);
    short* Wpb = (short*)(ws + 221184);
    short* qb  = (short*)(ws + 294912);
    short* kb  = (short*)(ws + 294912 + 26542080);
    short* vb  = (short*)(ws + 294912 + 26542080 + 79626240);
    short* ob  = (short*)(ws + 294912 + 26542080 + 79626240 + 79626240);
    // total: 212,631,552 bytes (same as round 2)

    hipLaunchKernelGGL(kW, dim3(576), dim3(256), 0, stream, w_qkv, w_proj, Wb, Wpb);
    hipLaunchKernelGGL(kA, dim3(3456), dim3(256), 0, stream, x, Wb, b_qkv, shiftp, qb, kb, vb, pred_q);
    hipLaunchKernelGGL(kB, dim3(NWIN * 6), dim3(256), 0, stream, qb, kb, vb, rpb, ob);
    hipLaunchKernelGGL(kC, dim3(NWIN), dim3(256), 0, stream, ob, Wpb, b_proj, shiftp, xo, x_pred);
}

// Round 5
// 419.506 us; speedup vs baseline: 9.2574x; 1.1074x over previous
//
#include <hip/hip_runtime.h>
#include <hip/hip_bf16.h>

// x: (2, 3, 192, 192, 180) fp32 ; windows: 1152 of 192 tokens (3x8x8); heads 6 x 30
#define NWIN 1152

// Output layout (floats): xo (2*192*192*181) | pred_q (1152*64*180) | x_pred (1152*64*180)
#define XO_ELEMS   13344768
#define PRED_ELEMS 13271040

typedef __attribute__((ext_vector_type(8))) short short8v;
typedef __attribute__((ext_vector_type(4))) float f32x4;

__device__ inline short bfbits(float f) {
    __hip_bfloat16 h = __float2bfloat16(f);
    return *reinterpret_cast<short*>(&h);
}

__device__ inline void load_shift(const int* sp, int& s0, int& s1, int& s2) {
    // shift_size may arrive as int32[3] or raw int64[3] (odd slots = high words).
    int v0 = sp[0], v1 = sp[1], v2 = sp[2], v3 = sp[3], v4 = sp[4], v5 = sp[5];
    if (v1 == 0 && v3 == 0 && v5 == 0) { s0 = v0; s1 = v2; s2 = v4; }
    else { s0 = v0; s1 = v1; s2 = v2; }
    s0 = ((s0 % 3) + 3) % 3;
    s1 = ((s1 % 192) + 192) % 192;
    s2 = ((s2 % 192) + 192) % 192;
}

// ---------------------------------------------------------------------------
// kW: one-shot weight conversion to padded bf16.
// ---------------------------------------------------------------------------
__global__ __launch_bounds__(256) void kW(const float* __restrict__ wq,
                                          const float* __restrict__ wp,
                                          short* __restrict__ Wb, short* __restrict__ Wpb) {
    int idx = blockIdx.x * 256 + threadIdx.x;
    if (idx < 576 * 192) {
        int n = idx / 192, k = idx - n * 192;
        Wb[idx] = (n < 540 && k < 180) ? bfbits(wq[n * 180 + k]) : (short)0;
    } else {
        idx -= 576 * 192;
        if (idx < 192 * 192) {
            int n = idx / 192, k = idx - n * 192;
            Wpb[idx] = (n < 180 && k < 180) ? bfbits(wp[n * 180 + k]) : (short)0;
        }
    }
}

// ---------------------------------------------------------------------------
// kA: QKV projection via MFMA, swapped operands (rows = n, cols = tokens).
// One block = 64 tokens, 9 n-subtiles of 64. W tile prefetched into regs
// during compute of the previous subtile (T14 split). Epilogue: float4 bias,
// short2-pair stores (each lane owns 4 consecutive n for one token).
// ---------------------------------------------------------------------------
__global__ __launch_bounds__(256) void kA(
    const float* __restrict__ x, const short* __restrict__ Wb, const float* __restrict__ bq,
    const int* __restrict__ shiftp,
    short* __restrict__ qb, short* __restrict__ kb, short* __restrict__ vb,
    float* __restrict__ predq)
{
    __shared__ short As[64 * 200];   // [tok][k], stride 200
    __shared__ short Ws[64 * 200];   // [n][k]
    __shared__ int rowbase[64];
    int s0, s1, s2; load_shift(shiftp, s0, s1, s2);
    const int tile = blockIdx.x;          // 3456
    const int tid  = threadIdx.x;
    const int g0   = tile * 64;
    const int win  = tile / 3;
    const int ntokbase = (tile - win * 3) * 64;
    const bool isq = (ntokbase == 128);

    if (tid < 64) {
        int g = g0 + tid;
        int n = g - win * 192;
        int d = n >> 6;
        int rem = n & 63;
        int i = rem >> 3, j = rem & 7;
        int bb = win / 576;
        int hw = win - bb * 576;
        int hj = hw / 24, wj = hw - hj * 24;
        int t = d + s0; if (t >= 3) t -= 3;
        int ho = hj * 8 + i + s1; if (ho >= 192) ho -= 192;
        int wo = wj * 8 + j + s2; if (wo >= 192) wo -= 192;
        rowbase[tid] = (((bb * 3 + t) * 192 + ho) * 192 + wo) * 180;
    }
    __syncthreads();
    // stage A tokens: fp32 -> bf16 (and exact fp32 pred_q for the query tile)
    for (int idx = tid; idx < 64 * 45; idx += 256) {
        int r = idx / 45, c4 = idx - r * 45;
        float4 v = *(const float4*)(x + rowbase[r] + c4 * 4);
        if (isq) *(float4*)(predq + (win * 64 + r) * 180 + c4 * 4) = v;
        short4 s = make_short4(bfbits(v.x), bfbits(v.y), bfbits(v.z), bfbits(v.w));
        *(short4*)(&As[r * 200 + c4 * 4]) = s;
    }
    if (tid < 192) {
        int r = tid / 3, p = tid - r * 3;
        *(short4*)(&As[r * 200 + 180 + p * 4]) = make_short4(0, 0, 0, 0);
    }

    // W prefetch machinery: 64 rows x 192 shorts = 1536 short8 chunks, 6/thread
    int wrow[6], wcol[6];
    short8v wreg[6];
    #pragma unroll
    for (int j = 0; j < 6; ++j) {
        int c = tid + j * 256;
        wrow[j] = c / 24;
        wcol[j] = (c - wrow[j] * 24) * 8;
    }
    #pragma unroll
    for (int j = 0; j < 6; ++j)
        wreg[j] = *(const short8v*)(Wb + wrow[j] * 192 + wcol[j]);
    #pragma unroll
    for (int j = 0; j < 6; ++j)
        *(short8v*)(&Ws[wrow[j] * 200 + wcol[j]]) = wreg[j];

    const int l  = tid & 63;
    const int w  = tid >> 6;
    const int wm = w >> 1, wn = w & 1;     // wm: n half, wn: token half
    const int lr = l & 15, lg = l >> 4;

    for (int ns = 0; ns < 9; ++ns) {
        __syncthreads();   // Ws[ns] (and As on first iter) visible
        if (ns < 8) {      // issue next W tile loads; land in regs under compute
            #pragma unroll
            for (int j = 0; j < 6; ++j)
                wreg[j] = *(const short8v*)(Wb + ((ns + 1) * 64 + wrow[j]) * 192 + wcol[j]);
        }
        f32x4 acc[2][2];
        #pragma unroll
        for (int i = 0; i < 2; ++i)
            #pragma unroll
            for (int j = 0; j < 2; ++j) acc[i][j] = (f32x4){0.f, 0.f, 0.f, 0.f};
        #pragma unroll
        for (int kk = 0; kk < 6; ++kk) {
            int k0 = kk * 32 + lg * 8;
            short8v wa0 = *(const short8v*)(&Ws[(wm * 32 + lr) * 200 + k0]);
            short8v wa1 = *(const short8v*)(&Ws[(wm * 32 + 16 + lr) * 200 + k0]);
            short8v tb0 = *(const short8v*)(&As[(wn * 32 + lr) * 200 + k0]);
            short8v tb1 = *(const short8v*)(&As[(wn * 32 + 16 + lr) * 200 + k0]);
            acc[0][0] = __builtin_amdgcn_mfma_f32_16x16x32_bf16(wa0, tb0, acc[0][0], 0, 0, 0);
            acc[0][1] = __builtin_amdgcn_mfma_f32_16x16x32_bf16(wa0, tb1, acc[0][1], 0, 0, 0);
            acc[1][0] = __builtin_amdgcn_mfma_f32_16x16x32_bf16(wa1, tb0, acc[1][0], 0, 0, 0);
            acc[1][1] = __builtin_amdgcn_mfma_f32_16x16x32_bf16(wa1, tb1, acc[1][1], 0, 0, 0);
        }
        // epilogue: rows = n (4 consecutive per lane), cols = tokens
        #pragma unroll
        for (int af = 0; af < 2; ++af) {
            int n0 = ns * 64 + wm * 32 + af * 16 + lg * 4;
            if (n0 >= 540) continue;
            float4 bias = *(const float4*)(bq + n0);
            int which = (n0 >= 360) ? 2 : (n0 >= 180) ? 1 : 0;
            if (which == 0 && !isq) continue;
            int hrem = n0 - which * 180;
            int head = (hrem * 137) >> 12;   // hrem/30, exact for 0..179
            int dd = hrem - head * 30;
            #pragma unroll
            for (int bf = 0; bf < 2; ++bf) {
                int ntok = ntokbase + wn * 32 + bf * 16 + lr;
                float v0 = acc[af][bf][0] + bias.x;
                float v1 = acc[af][bf][1] + bias.y;
                float v2 = acc[af][bf][2] + bias.z;
                float v3 = acc[af][bf][3] + bias.w;
                short* base;
                int hstride;
                if (which == 0) {
                    const float sc = 0.18257418583505536f;  // 30^-0.5
                    v0 *= sc; v1 *= sc; v2 *= sc; v3 *= sc;
                    base = qb + (win * 6 + head) * 1920 + (ntok - 128) * 30 + dd;
                    hstride = 1920;
                } else {
                    base = (which == 1 ? kb : vb) + (win * 6 + head) * 5760 + ntok * 30 + dd;
                    hstride = 5760;
                }
                *(short2*)(base) = make_short2(bfbits(v0), bfbits(v1));
                short* hi = (dd <= 26) ? (base + 2) : (base + hstride - 28);
                *(short2*)(hi) = make_short2(bfbits(v2), bfbits(v3));
            }
        }
        __syncthreads();   // all waves done reading Ws
        if (ns < 8) {
            #pragma unroll
            for (int j = 0; j < 6; ++j)
                *(short8v*)(&Ws[wrow[j] * 200 + wcol[j]]) = wreg[j];
        }
    }
}

// ---------------------------------------------------------------------------
// kB: MFMA attention (unchanged, verified round 4).
// ---------------------------------------------------------------------------
__global__ __launch_bounds__(256) void kB(
    const short* __restrict__ qb, const short* __restrict__ kb,
    const short* __restrict__ vb, const float* __restrict__ rpb,
    short* __restrict__ ob)
{
    __shared__ __attribute__((aligned(16))) short Ql[64 * 40];
    __shared__ __attribute__((aligned(16))) short Kl[192 * 40];
    __shared__ __attribute__((aligned(16))) short Vt[32 * 200];
    __shared__ __attribute__((aligned(16))) short Pl[64 * 200];
    __shared__ float rpbl[675];
    const int blk = blockIdx.x;
    const int win = blk / 6, head = blk - win * 6;
    const int tid = threadIdx.x;

    const short* qsrc = qb + (win * 6 + head) * 64 * 30;
    const short* ksrc = kb + (win * 6 + head) * 192 * 30;
    const short* vsrc = vb + (win * 6 + head) * 192 * 30;

    for (int i = tid; i < 960; i += 256) {
        int v = ((const int*)qsrc)[i];
        int f = 2 * i;
        int t = f / 30, d = f - t * 30;
        Ql[t * 40 + d] = (short)(v & 0xffff);
        Ql[t * 40 + d + 1] = (short)((unsigned)v >> 16);
    }
    for (int i = tid; i < 2880; i += 256) {
        int v = ((const int*)ksrc)[i];
        int f = 2 * i;
        int t = f / 30, d = f - t * 30;
        Kl[t * 40 + d] = (short)(v & 0xffff);
        Kl[t * 40 + d + 1] = (short)((unsigned)v >> 16);
    }
    for (int i = tid; i < 2880; i += 256) {
        int v = ((const int*)vsrc)[i];
        int f = 2 * i;
        int t = f / 30, d = f - t * 30;
        Vt[d * 200 + t] = (short)(v & 0xffff);
        Vt[(d + 1) * 200 + t] = (short)((unsigned)v >> 16);
    }
    if (tid < 64)  *(int*)(&Ql[tid * 40 + 30]) = 0;
    if (tid < 192) *(int*)(&Kl[tid * 40 + 30]) = 0;
    if (tid < 50)  *(short8v*)(&Vt[30 * 200 + tid * 8]) = (short8v){0,0,0,0,0,0,0,0};
    for (int i = tid; i < 675; i += 256) rpbl[i] = rpb[i * 6 + head];
    __syncthreads();

    const int l  = tid & 63;
    const int w  = tid >> 6;
    const int lr = l & 15, lg = l >> 4;
    const int rowbase = w * 16;

    short8v aq = *(const short8v*)(&Ql[(rowbase + lr) * 40 + lg * 8]);
    f32x4 s[12];
    #pragma unroll
    for (int f = 0; f < 12; ++f) {
        short8v b = *(const short8v*)(&Kl[(f * 16 + lr) * 40 + lg * 8]);
        s[f] = __builtin_amdgcn_mfma_f32_16x16x32_bf16(aq, b, (f32x4){0.f, 0.f, 0.f, 0.f}, 0, 0, 0);
    }

    int cr[4];
    #pragma unroll
    for (int r = 0; r < 4; ++r) {
        int qi = rowbase + lg * 4 + r;
        int yi = qi >> 3, xi = qi & 7;
        cr[r] = yi * 15 + xi + 112;
    }
    #pragma unroll
    for (int f = 0; f < 12; ++f) {
        int kc = f * 16 + lr;
        int dk = kc >> 6;
        int rm = kc & 63;
        int yk = rm >> 3, xk = rm & 7;
        int koff = (2 - dk) * 225 - yk * 15 - xk;
        #pragma unroll
        for (int r = 0; r < 4; ++r) s[f][r] += rpbl[cr[r] + koff];
    }
    float m0 = s[0][0], m1 = s[0][1], m2 = s[0][2], m3 = s[0][3];
    #pragma unroll
    for (int f = 1; f < 12; ++f) {
        m0 = fmaxf(m0, s[f][0]); m1 = fmaxf(m1, s[f][1]);
        m2 = fmaxf(m2, s[f][2]); m3 = fmaxf(m3, s[f][3]);
    }
    #pragma unroll
    for (int d = 1; d < 16; d <<= 1) {
        m0 = fmaxf(m0, __shfl_xor(m0, d)); m1 = fmaxf(m1, __shfl_xor(m1, d));
        m2 = fmaxf(m2, __shfl_xor(m2, d)); m3 = fmaxf(m3, __shfl_xor(m3, d));
    }
    float d0 = 0.f, d1 = 0.f, d2 = 0.f, d3 = 0.f;
    #pragma unroll
    for (int f = 0; f < 12; ++f) {
        float p0 = __expf(s[f][0] - m0); d0 += p0;
        float p1 = __expf(s[f][1] - m1); d1 += p1;
        float p2 = __expf(s[f][2] - m2); d2 += p2;
        float p3 = __expf(s[f][3] - m3); d3 += p3;
        int col = f * 16 + lr;
        Pl[(rowbase + lg * 4 + 0) * 200 + col] = bfbits(p0);
        Pl[(rowbase + lg * 4 + 1) * 200 + col] = bfbits(p1);
        Pl[(rowbase + lg * 4 + 2) * 200 + col] = bfbits(p2);
        Pl[(rowbase + lg * 4 + 3) * 200 + col] = bfbits(p3);
    }
    #pragma unroll
    for (int d = 1; d < 16; d <<= 1) {
        d0 += __shfl_xor(d0, d); d1 += __shfl_xor(d1, d);
        d2 += __shfl_xor(d2, d); d3 += __shfl_xor(d3, d);
    }
    float inv[4] = {1.f / d0, 1.f / d1, 1.f / d2, 1.f / d3};

    f32x4 o0 = (f32x4){0.f, 0.f, 0.f, 0.f};
    f32x4 o1 = (f32x4){0.f, 0.f, 0.f, 0.f};
    #pragma unroll
    for (int ks = 0; ks < 6; ++ks) {
        int k0 = ks * 32 + lg * 8;
        short8v pa = *(const short8v*)(&Pl[(rowbase + lr) * 200 + k0]);
        short8v b0 = *(const short8v*)(&Vt[lr * 200 + k0]);
        short8v b1 = *(const short8v*)(&Vt[(16 + lr) * 200 + k0]);
        o0 = __builtin_amdgcn_mfma_f32_16x16x32_bf16(pa, b0, o0, 0, 0, 0);
        o1 = __builtin_amdgcn_mfma_f32_16x16x32_bf16(pa, b1, o1, 0, 0, 0);
    }
    #pragma unroll
    for (int r = 0; r < 4; ++r) {
        int qi = rowbase + lg * 4 + r;
        short* dst = ob + ((win * 64 + qi) * 6 + head) * 30;
        dst[lr] = bfbits(o0[r] * inv[r]);
        if (lr < 14) dst[16 + lr] = bfbits(o1[r] * inv[r]);
    }
}

// ---------------------------------------------------------------------------
// kC: output projection via MFMA, swapped operands + W prefetch.
// Rows = n (proj channel), cols = tokens. float4 x_pred stores; xo scalar
// (stride-181 rows are not 16B-alignable).
// ---------------------------------------------------------------------------
__global__ __launch_bounds__(256) void kC(
    const short* __restrict__ ob, const short* __restrict__ Wpb, const float* __restrict__ bp,
    const int* __restrict__ shiftp, float* __restrict__ xo, float* __restrict__ xpred)
{
    __shared__ short As[64 * 200];
    __shared__ short Ws[64 * 200];
    int s0, s1, s2; load_shift(shiftp, s0, s1, s2);
    const int win = blockIdx.x;
    const int tid = threadIdx.x;
    const int bb = win / 576;
    const int hw = win - bb * 576;
    const int hj = hw / 24, wj = hw - hj * 24;

    const short* src = ob + win * 64 * 180;
    for (int idx = tid; idx < 64 * 45; idx += 256) {
        int r = idx / 45, c4 = idx - r * 45;
        *(short4*)(&As[r * 200 + c4 * 4]) = *(const short4*)(src + r * 180 + c4 * 4);
    }
    if (tid < 192) {
        int r = tid / 3, p = tid - r * 3;
        *(short4*)(&As[r * 200 + 180 + p * 4]) = make_short4(0, 0, 0, 0);
    }

    int wrow[6], wcol[6];
    short8v wreg[6];
    #pragma unroll
    for (int j = 0; j < 6; ++j) {
        int c = tid + j * 256;
        wrow[j] = c / 24;
        wcol[j] = (c - wrow[j] * 24) * 8;
    }
    #pragma unroll
    for (int j = 0; j < 6; ++j)
        wreg[j] = *(const short8v*)(Wpb + wrow[j] * 192 + wcol[j]);
    #pragma unroll
    for (int j = 0; j < 6; ++j)
        *(short8v*)(&Ws[wrow[j] * 200 + wcol[j]]) = wreg[j];

    const int l  = tid & 63;
    const int w  = tid >> 6;
    const int wm = w >> 1, wn = w & 1;
    const int lr = l & 15, lg = l >> 4;

    for (int ns = 0; ns < 3; ++ns) {
        __syncthreads();
        if (ns < 2) {
            #pragma unroll
            for (int j = 0; j < 6; ++j)
                wreg[j] = *(const short8v*)(Wpb + ((ns + 1) * 64 + wrow[j]) * 192 + wcol[j]);
        }
        f32x4 acc[2][2];
        #pragma unroll
        for (int i = 0; i < 2; ++i)
            #pragma unroll
            for (int j = 0; j < 2; ++j) acc[i][j] = (f32x4){0.f, 0.f, 0.f, 0.f};
        #pragma unroll
        for (int kk = 0; kk < 6; ++kk) {
            int k0 = kk * 32 + lg * 8;
            short8v wa0 = *(const short8v*)(&Ws[(wm * 32 + lr) * 200 + k0]);
            short8v wa1 = *(const short8v*)(&Ws[(wm * 32 + 16 + lr) * 200 + k0]);
            short8v tb0 = *(const short8v*)(&As[(wn * 32 + lr) * 200 + k0]);
            short8v tb1 = *(const short8v*)(&As[(wn * 32 + 16 + lr) * 200 + k0]);
            acc[0][0] = __builtin_amdgcn_mfma_f32_16x16x32_bf16(wa0, tb0, acc[0][0], 0, 0, 0);
            acc[0][1] = __builtin_amdgcn_mfma_f32_16x16x32_bf16(wa0, tb1, acc[0][1], 0, 0, 0);
            acc[1][0] = __builtin_amdgcn_mfma_f32_16x16x32_bf16(wa1, tb0, acc[1][0], 0, 0, 0);
            acc[1][1] = __builtin_amdgcn_mfma_f32_16x16x32_bf16(wa1, tb1, acc[1][1], 0, 0, 0);
        }
        #pragma unroll
        for (int bf = 0; bf < 2; ++bf) {
            int qi = wn * 32 + bf * 16 + lr;
            int i = qi >> 3, j = qi & 7;
            int ho = hj * 8 + i + s1; if (ho >= 192) ho -= 192;
            int wo = wj * 8 + j + s2; if (wo >= 192) wo -= 192;
            float* xrow = xo + ((bb * 192 + ho) * 192 + wo) * 181;
            float* prow = xpred + (win * 64 + qi) * 180;
            #pragma unroll
            for (int af = 0; af < 2; ++af) {
                int n0 = ns * 64 + wm * 32 + af * 16 + lg * 4;
                if (n0 >= 180) continue;
                float4 bias = *(const float4*)(bp + n0);
                float v0 = acc[af][bf][0] + bias.x;
                float v1 = acc[af][bf][1] + bias.y;
                float v2 = acc[af][bf][2] + bias.z;
                float v3 = acc[af][bf][3] + bias.w;
                xrow[n0] = v0; xrow[n0 + 1] = v1; xrow[n0 + 2] = v2; xrow[n0 + 3] = v3;
                *(float4*)(prow + n0) = make_float4(v0, v1, v2, v3);
            }
            if (ns == 0 && wm == 0 && lg == 0) xrow[180] = 1.0f;
        }
        __syncthreads();
        if (ns < 2) {
            #pragma unroll
            for (int j = 0; j < 6; ++j)
                *(short8v*)(&Ws[wrow[j] * 200 + wcol[j]]) = wreg[j];
        }
    }
}

// ---------------------------------------------------------------------------
extern "C" void kernel_launch(void* const* d_in, const int* in_sizes, int n_in,
                              void* d_out, int out_size, void* d_ws, size_t ws_size,
                              hipStream_t stream) {
    const float* x      = (const float*)d_in[0];
    const float* w_qkv  = (const float*)d_in[1];
    const float* b_qkv  = (const float*)d_in[2];
    const float* w_proj = (const float*)d_in[3];
    const float* b_proj = (const float*)d_in[4];
    const float* rpb    = (const float*)d_in[5];
    const int*   shiftp = (const int*)d_in[6];

    float* out    = (float*)d_out;
    float* xo     = out;
    float* pred_q = out + XO_ELEMS;
    float* x_pred = out + XO_ELEMS + PRED_ELEMS;

    // ws layout (bytes): Wb 221184 | Wpb 73728 | qb 26542080 | kb 79626240 | vb 79626240 | ob 26542080
    char* ws = (char*)d_ws;
    short* Wb  = (short*)(ws);
    short* Wpb = (short*)(ws + 221184);
    short* qb  = (short*)(ws + 294912);
    short* kb  = (short*)(ws + 294912 + 26542080);
    short* vb  = (short*)(ws + 294912 + 26542080 + 79626240);
    short* ob  = (short*)(ws + 294912 + 26542080 + 79626240 + 79626240);
    // total: 212,631,552 bytes

    hipLaunchKernelGGL(kW, dim3(576), dim3(256), 0, stream, w_qkv, w_proj, Wb, Wpb);
    hipLaunchKernelGGL(kA, dim3(3456), dim3(256), 0, stream, x, Wb, b_qkv, shiftp, qb, kb, vb, pred_q);
    hipLaunchKernelGGL(kB, dim3(NWIN * 6), dim3(256), 0, stream, qb, kb, vb, rpb, ob);
    hipLaunchKernelGGL(kC, dim3(NWIN), dim3(256), 0, stream, ob, Wpb, b_proj, shiftp, xo, x_pred);
}

// Round 6
// 297.480 us; speedup vs baseline: 13.0548x; 1.4102x over previous
//
#include <hip/hip_runtime.h>
#include <hip/hip_bf16.h>

// x: (2, 3, 192, 192, 180) fp32 ; windows: 1152 of 192 tokens (3x8x8); heads 6 x 30
#define NWIN 1152

// Output layout (floats): xo (2*192*192*181) | pred_q (1152*64*180) | x_pred (1152*64*180)
#define XO_ELEMS   13344768
#define PRED_ELEMS 13271040

typedef __attribute__((ext_vector_type(8))) short short8v;
typedef __attribute__((ext_vector_type(4))) float f32x4;

__device__ inline short bfbits(float f) {
    __hip_bfloat16 h = __float2bfloat16(f);
    return *reinterpret_cast<short*>(&h);
}

__device__ inline void load_shift(const int* sp, int& s0, int& s1, int& s2) {
    // shift_size may arrive as int32[3] or raw int64[3] (odd slots = high words).
    int v0 = sp[0], v1 = sp[1], v2 = sp[2], v3 = sp[3], v4 = sp[4], v5 = sp[5];
    if (v1 == 0 && v3 == 0 && v5 == 0) { s0 = v0; s1 = v2; s2 = v4; }
    else { s0 = v0; s1 = v1; s2 = v2; }
    s0 = ((s0 % 3) + 3) % 3;
    s1 = ((s1 % 192) + 192) % 192;
    s2 = ((s2 % 192) + 192) % 192;
}

// ---------------------------------------------------------------------------
// kW: one-shot weight conversion to padded bf16.
// ---------------------------------------------------------------------------
__global__ __launch_bounds__(256) void kW(const float* __restrict__ wq,
                                          const float* __restrict__ wp,
                                          short* __restrict__ Wb, short* __restrict__ Wpb) {
    int idx = blockIdx.x * 256 + threadIdx.x;
    if (idx < 576 * 192) {
        int n = idx / 192, k = idx - n * 192;
        Wb[idx] = (n < 540 && k < 180) ? bfbits(wq[n * 180 + k]) : (short)0;
    } else {
        idx -= 576 * 192;
        if (idx < 192 * 192) {
            int n = idx / 192, k = idx - n * 192;
            Wpb[idx] = (n < 180 && k < 180) ? bfbits(wp[n * 180 + k]) : (short)0;
        }
    }
}

// ---------------------------------------------------------------------------
// kA: QKV projection via MFMA, swapped operands (rows = n, cols = tokens).
// q/k written stride-30 as before; v written TRANSPOSED: vt[win][head][dd][192].
// dd == 2*head (mod 4), so 4-runs cross a head boundary only at dd==28
// (even heads) -> rows land in head+1 <= 5, always in-window.
// ---------------------------------------------------------------------------
__global__ __launch_bounds__(256) void kA(
    const float* __restrict__ x, const short* __restrict__ Wb, const float* __restrict__ bq,
    const int* __restrict__ shiftp,
    short* __restrict__ qb, short* __restrict__ kb, short* __restrict__ vtb,
    float* __restrict__ predq)
{
    __shared__ short As[64 * 200];   // [tok][k], stride 200
    __shared__ short Ws[64 * 200];   // [n][k]
    __shared__ int rowbase[64];
    int s0, s1, s2; load_shift(shiftp, s0, s1, s2);
    const int tile = blockIdx.x;          // 3456
    const int tid  = threadIdx.x;
    const int g0   = tile * 64;
    const int win  = tile / 3;
    const int ntokbase = (tile - win * 3) * 64;
    const bool isq = (ntokbase == 128);

    if (tid < 64) {
        int g = g0 + tid;
        int n = g - win * 192;
        int d = n >> 6;
        int rem = n & 63;
        int i = rem >> 3, j = rem & 7;
        int bb = win / 576;
        int hw = win - bb * 576;
        int hj = hw / 24, wj = hw - hj * 24;
        int t = d + s0; if (t >= 3) t -= 3;
        int ho = hj * 8 + i + s1; if (ho >= 192) ho -= 192;
        int wo = wj * 8 + j + s2; if (wo >= 192) wo -= 192;
        rowbase[tid] = (((bb * 3 + t) * 192 + ho) * 192 + wo) * 180;
    }
    __syncthreads();
    // stage A tokens: fp32 -> bf16 (and exact fp32 pred_q for the query tile)
    for (int idx = tid; idx < 64 * 45; idx += 256) {
        int r = idx / 45, c4 = idx - r * 45;
        float4 v = *(const float4*)(x + rowbase[r] + c4 * 4);
        if (isq) *(float4*)(predq + (win * 64 + r) * 180 + c4 * 4) = v;
        short4 s = make_short4(bfbits(v.x), bfbits(v.y), bfbits(v.z), bfbits(v.w));
        *(short4*)(&As[r * 200 + c4 * 4]) = s;
    }
    if (tid < 192) {
        int r = tid / 3, p = tid - r * 3;
        *(short4*)(&As[r * 200 + 180 + p * 4]) = make_short4(0, 0, 0, 0);
    }

    // W prefetch machinery: 64 rows x 192 shorts = 1536 short8 chunks, 6/thread
    int wrow[6], wcol[6];
    short8v wreg[6];
    #pragma unroll
    for (int j = 0; j < 6; ++j) {
        int c = tid + j * 256;
        wrow[j] = c / 24;
        wcol[j] = (c - wrow[j] * 24) * 8;
    }
    #pragma unroll
    for (int j = 0; j < 6; ++j)
        wreg[j] = *(const short8v*)(Wb + wrow[j] * 192 + wcol[j]);
    #pragma unroll
    for (int j = 0; j < 6; ++j)
        *(short8v*)(&Ws[wrow[j] * 200 + wcol[j]]) = wreg[j];

    const int l  = tid & 63;
    const int w  = tid >> 6;
    const int wm = w >> 1, wn = w & 1;     // wm: n half, wn: token half
    const int lr = l & 15, lg = l >> 4;

    for (int ns = 0; ns < 9; ++ns) {
        __syncthreads();   // Ws[ns] (and As on first iter) visible
        if (ns < 8) {      // issue next W tile loads; land in regs under compute
            #pragma unroll
            for (int j = 0; j < 6; ++j)
                wreg[j] = *(const short8v*)(Wb + ((ns + 1) * 64 + wrow[j]) * 192 + wcol[j]);
        }
        f32x4 acc[2][2];
        #pragma unroll
        for (int i = 0; i < 2; ++i)
            #pragma unroll
            for (int j = 0; j < 2; ++j) acc[i][j] = (f32x4){0.f, 0.f, 0.f, 0.f};
        #pragma unroll
        for (int kk = 0; kk < 6; ++kk) {
            int k0 = kk * 32 + lg * 8;
            short8v wa0 = *(const short8v*)(&Ws[(wm * 32 + lr) * 200 + k0]);
            short8v wa1 = *(const short8v*)(&Ws[(wm * 32 + 16 + lr) * 200 + k0]);
            short8v tb0 = *(const short8v*)(&As[(wn * 32 + lr) * 200 + k0]);
            short8v tb1 = *(const short8v*)(&As[(wn * 32 + 16 + lr) * 200 + k0]);
            acc[0][0] = __builtin_amdgcn_mfma_f32_16x16x32_bf16(wa0, tb0, acc[0][0], 0, 0, 0);
            acc[0][1] = __builtin_amdgcn_mfma_f32_16x16x32_bf16(wa0, tb1, acc[0][1], 0, 0, 0);
            acc[1][0] = __builtin_amdgcn_mfma_f32_16x16x32_bf16(wa1, tb0, acc[1][0], 0, 0, 0);
            acc[1][1] = __builtin_amdgcn_mfma_f32_16x16x32_bf16(wa1, tb1, acc[1][1], 0, 0, 0);
        }
        // epilogue: rows = n (4 consecutive per lane), cols = tokens
        #pragma unroll
        for (int af = 0; af < 2; ++af) {
            int n0 = ns * 64 + wm * 32 + af * 16 + lg * 4;
            if (n0 >= 540) continue;
            float4 bias = *(const float4*)(bq + n0);
            int which = (n0 >= 360) ? 2 : (n0 >= 180) ? 1 : 0;
            if (which == 0 && !isq) continue;
            int hrem = n0 - which * 180;
            int head = (hrem * 137) >> 12;   // hrem/30, exact for 0..179
            int dd = hrem - head * 30;
            #pragma unroll
            for (int bf = 0; bf < 2; ++bf) {
                int ntok = ntokbase + wn * 32 + bf * 16 + lr;
                float v0 = acc[af][bf][0] + bias.x;
                float v1 = acc[af][bf][1] + bias.y;
                float v2 = acc[af][bf][2] + bias.z;
                float v3 = acc[af][bf][3] + bias.w;
                if (which == 2) {
                    // transposed V: vt[head][dd][tok]; dd+r>29 -> next head row
                    short* vh = vtb + (win * 6 + head) * 5760 + ntok;
                    float vr[4] = {v0, v1, v2, v3};
                    #pragma unroll
                    for (int r = 0; r < 4; ++r) {
                        int drow = dd + r;
                        int off = (drow <= 29) ? drow * 192 : (5760 + (drow - 30) * 192);
                        vh[off] = bfbits(vr[r]);
                    }
                } else {
                    short* base;
                    int hstride;
                    if (which == 0) {
                        const float sc = 0.18257418583505536f;  // 30^-0.5
                        v0 *= sc; v1 *= sc; v2 *= sc; v3 *= sc;
                        base = qb + (win * 6 + head) * 1920 + (ntok - 128) * 30 + dd;
                        hstride = 1920;
                    } else {
                        base = kb + (win * 6 + head) * 5760 + ntok * 30 + dd;
                        hstride = 5760;
                    }
                    *(short2*)(base) = make_short2(bfbits(v0), bfbits(v1));
                    short* hi = (dd <= 26) ? (base + 2) : (base + hstride - 28);
                    *(short2*)(hi) = make_short2(bfbits(v2), bfbits(v3));
                }
            }
        }
        __syncthreads();   // all waves done reading Ws
        if (ns < 8) {
            #pragma unroll
            for (int j = 0; j < 6; ++j)
                *(short8v*)(&Ws[wrow[j] * 200 + wcol[j]]) = wreg[j];
        }
    }
}

// ---------------------------------------------------------------------------
// kB: MFMA attention, vectorized staging + K/P LDS overlay.
// Q/K staged as int4 chunks from stride-30 buffers into stride-32 LDS rows:
// Q pad shorts (30,31) forced 0; K pads carry next-row leakage (finite) which
// is cancelled by Q's zeros in the MFMA k-sum. V staged linearly from the
// transposed vt buffer. P overlays the dead K region (barrier in between).
// ---------------------------------------------------------------------------
__global__ __launch_bounds__(256) void kB(
    const short* __restrict__ qb, const short* __restrict__ kb,
    const short* __restrict__ vt, const float* __restrict__ rpb,
    short* __restrict__ ob)
{
    __shared__ __attribute__((aligned(16))) short Ql[64 * 32];    //  4096 B
    __shared__ __attribute__((aligned(16))) short KP[64 * 200];   // 25600 B: Kl(192x32) then Pl(64x200)
    __shared__ __attribute__((aligned(16))) short Vt[32 * 200];   // 12800 B (rows 30,31 unused)
    __shared__ float rpbl[675];
    const int blk = blockIdx.x;
    const int win = blk / 6, head = blk - win * 6;
    const int tid = threadIdx.x;

    const short* qsrc = qb + (win * 6 + head) * 1920;
    const short* ksrc = kb + (win * 6 + head) * 5760;
    const short* vsrc = vt + (win * 6 + head) * 5760;

    // Q: 64 rows x 4 int4-chunks; chunk 3 zero-tops the pad shorts
    {
        int row = tid >> 2, q = tid & 3;
        const int* p = (const int*)(qsrc + row * 30 + q * 8);
        int b3 = (q == 3) ? 0 : p[3];
        *(int4*)(&Ql[row * 32 + q * 8]) = make_int4(p[0], p[1], p[2], b3);
    }
    // K: 192 rows x 4 chunks (pad shorts = next-row leak, cancelled by Q zeros)
    #pragma unroll
    for (int j = 0; j < 3; ++j) {
        int c = tid + j * 256;
        int row = c >> 2, q = c & 3;
        const int* p = (const int*)(ksrc + row * 30 + q * 8);
        *(int4*)(&KP[row * 32 + q * 8]) = make_int4(p[0], p[1], p[2], p[3]);
    }
    // V: 720 linear chunks into stride-200 rows
    #pragma unroll
    for (int j = 0; j < 3; ++j) {
        int c = tid + j * 256;
        if (c < 720) {
            int row = c / 24, col = c - row * 24;
            const int* p = (const int*)(vsrc + c * 8);
            *(int4*)(&Vt[row * 200 + col * 8]) = make_int4(p[0], p[1], p[2], p[3]);
        }
    }
    for (int i = tid; i < 675; i += 256) rpbl[i] = rpb[i * 6 + head];
    __syncthreads();

    const int l  = tid & 63;
    const int w  = tid >> 6;
    const int lr = l & 15, lg = l >> 4;
    const int rowbase = w * 16;

    // ---- QK^T ----
    short8v aq = *(const short8v*)(&Ql[(rowbase + lr) * 32 + lg * 8]);
    f32x4 s[12];
    #pragma unroll
    for (int f = 0; f < 12; ++f) {
        short8v b = *(const short8v*)(&KP[(f * 16 + lr) * 32 + lg * 8]);
        s[f] = __builtin_amdgcn_mfma_f32_16x16x32_bf16(aq, b, (f32x4){0.f, 0.f, 0.f, 0.f}, 0, 0, 0);
    }
    __syncthreads();   // K region dead; P may overwrite

    // ---- bias + softmax ----
    int cr[4];
    #pragma unroll
    for (int r = 0; r < 4; ++r) {
        int qi = rowbase + lg * 4 + r;
        int yi = qi >> 3, xi = qi & 7;
        cr[r] = yi * 15 + xi + 112;
    }
    #pragma unroll
    for (int f = 0; f < 12; ++f) {
        int kc = f * 16 + lr;
        int dk = kc >> 6;
        int rm = kc & 63;
        int yk = rm >> 3, xk = rm & 7;
        int koff = (2 - dk) * 225 - yk * 15 - xk;
        #pragma unroll
        for (int r = 0; r < 4; ++r) s[f][r] += rpbl[cr[r] + koff];
    }
    float m0 = s[0][0], m1 = s[0][1], m2 = s[0][2], m3 = s[0][3];
    #pragma unroll
    for (int f = 1; f < 12; ++f) {
        m0 = fmaxf(m0, s[f][0]); m1 = fmaxf(m1, s[f][1]);
        m2 = fmaxf(m2, s[f][2]); m3 = fmaxf(m3, s[f][3]);
    }
    #pragma unroll
    for (int d = 1; d < 16; d <<= 1) {
        m0 = fmaxf(m0, __shfl_xor(m0, d)); m1 = fmaxf(m1, __shfl_xor(m1, d));
        m2 = fmaxf(m2, __shfl_xor(m2, d)); m3 = fmaxf(m3, __shfl_xor(m3, d));
    }
    float d0 = 0.f, d1 = 0.f, d2 = 0.f, d3 = 0.f;
    #pragma unroll
    for (int f = 0; f < 12; ++f) {
        float p0 = __expf(s[f][0] - m0); d0 += p0;
        float p1 = __expf(s[f][1] - m1); d1 += p1;
        float p2 = __expf(s[f][2] - m2); d2 += p2;
        float p3 = __expf(s[f][3] - m3); d3 += p3;
        int col = f * 16 + lr;
        KP[(rowbase + lg * 4 + 0) * 200 + col] = bfbits(p0);
        KP[(rowbase + lg * 4 + 1) * 200 + col] = bfbits(p1);
        KP[(rowbase + lg * 4 + 2) * 200 + col] = bfbits(p2);
        KP[(rowbase + lg * 4 + 3) * 200 + col] = bfbits(p3);
    }
    #pragma unroll
    for (int d = 1; d < 16; d <<= 1) {
        d0 += __shfl_xor(d0, d); d1 += __shfl_xor(d1, d);
        d2 += __shfl_xor(d2, d); d3 += __shfl_xor(d3, d);
    }
    float inv[4] = {1.f / d0, 1.f / d1, 1.f / d2, 1.f / d3};

    // ---- PV ---- (wave reads only its own P rows; Vt rows 30/31 feed
    // discarded output cols 14/15 of o1)
    f32x4 o0 = (f32x4){0.f, 0.f, 0.f, 0.f};
    f32x4 o1 = (f32x4){0.f, 0.f, 0.f, 0.f};
    #pragma unroll
    for (int ks = 0; ks < 6; ++ks) {
        int k0 = ks * 32 + lg * 8;
        short8v pa = *(const short8v*)(&KP[(rowbase + lr) * 200 + k0]);
        short8v b0 = *(const short8v*)(&Vt[lr * 200 + k0]);
        short8v b1 = *(const short8v*)(&Vt[(16 + lr) * 200 + k0]);
        o0 = __builtin_amdgcn_mfma_f32_16x16x32_bf16(pa, b0, o0, 0, 0, 0);
        o1 = __builtin_amdgcn_mfma_f32_16x16x32_bf16(pa, b1, o1, 0, 0, 0);
    }
    #pragma unroll
    for (int r = 0; r < 4; ++r) {
        int qi = rowbase + lg * 4 + r;
        short* dst = ob + ((win * 64 + qi) * 6 + head) * 30;
        dst[lr] = bfbits(o0[r] * inv[r]);
        if (lr < 14) dst[16 + lr] = bfbits(o1[r] * inv[r]);
    }
}

// ---------------------------------------------------------------------------
// kC: output projection via MFMA, swapped operands + W prefetch (unchanged).
// ---------------------------------------------------------------------------
__global__ __launch_bounds__(256) void kC(
    const short* __restrict__ ob, const short* __restrict__ Wpb, const float* __restrict__ bp,
    const int* __restrict__ shiftp, float* __restrict__ xo, float* __restrict__ xpred)
{
    __shared__ short As[64 * 200];
    __shared__ short Ws[64 * 200];
    int s0, s1, s2; load_shift(shiftp, s0, s1, s2);
    const int win = blockIdx.x;
    const int tid = threadIdx.x;
    const int bb = win / 576;
    const int hw = win - bb * 576;
    const int hj = hw / 24, wj = hw - hj * 24;

    const short* src = ob + win * 64 * 180;
    for (int idx = tid; idx < 64 * 45; idx += 256) {
        int r = idx / 45, c4 = idx - r * 45;
        *(short4*)(&As[r * 200 + c4 * 4]) = *(const short4*)(src + r * 180 + c4 * 4);
    }
    if (tid < 192) {
        int r = tid / 3, p = tid - r * 3;
        *(short4*)(&As[r * 200 + 180 + p * 4]) = make_short4(0, 0, 0, 0);
    }

    int wrow[6], wcol[6];
    short8v wreg[6];
    #pragma unroll
    for (int j = 0; j < 6; ++j) {
        int c = tid + j * 256;
        wrow[j] = c / 24;
        wcol[j] = (c - wrow[j] * 24) * 8;
    }
    #pragma unroll
    for (int j = 0; j < 6; ++j)
        wreg[j] = *(const short8v*)(Wpb + wrow[j] * 192 + wcol[j]);
    #pragma unroll
    for (int j = 0; j < 6; ++j)
        *(short8v*)(&Ws[wrow[j] * 200 + wcol[j]]) = wreg[j];

    const int l  = tid & 63;
    const int w  = tid >> 6;
    const int wm = w >> 1, wn = w & 1;
    const int lr = l & 15, lg = l >> 4;

    for (int ns = 0; ns < 3; ++ns) {
        __syncthreads();
        if (ns < 2) {
            #pragma unroll
            for (int j = 0; j < 6; ++j)
                wreg[j] = *(const short8v*)(Wpb + ((ns + 1) * 64 + wrow[j]) * 192 + wcol[j]);
        }
        f32x4 acc[2][2];
        #pragma unroll
        for (int i = 0; i < 2; ++i)
            #pragma unroll
            for (int j = 0; j < 2; ++j) acc[i][j] = (f32x4){0.f, 0.f, 0.f, 0.f};
        #pragma unroll
        for (int kk = 0; kk < 6; ++kk) {
            int k0 = kk * 32 + lg * 8;
            short8v wa0 = *(const short8v*)(&Ws[(wm * 32 + lr) * 200 + k0]);
            short8v wa1 = *(const short8v*)(&Ws[(wm * 32 + 16 + lr) * 200 + k0]);
            short8v tb0 = *(const short8v*)(&As[(wn * 32 + lr) * 200 + k0]);
            short8v tb1 = *(const short8v*)(&As[(wn * 32 + 16 + lr) * 200 + k0]);
            acc[0][0] = __builtin_amdgcn_mfma_f32_16x16x32_bf16(wa0, tb0, acc[0][0], 0, 0, 0);
            acc[0][1] = __builtin_amdgcn_mfma_f32_16x16x32_bf16(wa0, tb1, acc[0][1], 0, 0, 0);
            acc[1][0] = __builtin_amdgcn_mfma_f32_16x16x32_bf16(wa1, tb0, acc[1][0], 0, 0, 0);
            acc[1][1] = __builtin_amdgcn_mfma_f32_16x16x32_bf16(wa1, tb1, acc[1][1], 0, 0, 0);
        }
        #pragma unroll
        for (int bf = 0; bf < 2; ++bf) {
            int qi = wn * 32 + bf * 16 + lr;
            int i = qi >> 3, j = qi & 7;
            int ho = hj * 8 + i + s1; if (ho >= 192) ho -= 192;
            int wo = wj * 8 + j + s2; if (wo >= 192) wo -= 192;
            float* xrow = xo + ((bb * 192 + ho) * 192 + wo) * 181;
            float* prow = xpred + (win * 64 + qi) * 180;
            #pragma unroll
            for (int af = 0; af < 2; ++af) {
                int n0 = ns * 64 + wm * 32 + af * 16 + lg * 4;
                if (n0 >= 180) continue;
                float4 bias = *(const float4*)(bp + n0);
                float v0 = acc[af][bf][0] + bias.x;
                float v1 = acc[af][bf][1] + bias.y;
                float v2 = acc[af][bf][2] + bias.z;
                float v3 = acc[af][bf][3] + bias.w;
                xrow[n0] = v0; xrow[n0 + 1] = v1; xrow[n0 + 2] = v2; xrow[n0 + 3] = v3;
                *(float4*)(prow + n0) = make_float4(v0, v1, v2, v3);
            }
            if (ns == 0 && wm == 0 && lg == 0) xrow[180] = 1.0f;
        }
        __syncthreads();
        if (ns < 2) {
            #pragma unroll
            for (int j = 0; j < 6; ++j)
                *(short8v*)(&Ws[wrow[j] * 200 + wcol[j]]) = wreg[j];
        }
    }
}

// ---------------------------------------------------------------------------
extern "C" void kernel_launch(void* const* d_in, const int* in_sizes, int n_in,
                              void* d_out, int out_size, void* d_ws, size_t ws_size,
                              hipStream_t stream) {
    const float* x      = (const float*)d_in[0];
    const float* w_qkv  = (const float*)d_in[1];
    const float* b_qkv  = (const float*)d_in[2];
    const float* w_proj = (const float*)d_in[3];
    const float* b_proj = (const float*)d_in[4];
    const float* rpb    = (const float*)d_in[5];
    const int*   shiftp = (const int*)d_in[6];

    float* out    = (float*)d_out;
    float* xo     = out;
    float* pred_q = out + XO_ELEMS;
    float* x_pred = out + XO_ELEMS + PRED_ELEMS;

    // ws layout (bytes): Wb 221184 | Wpb 73728 | qb 26542080 | kb 79626240 | vt 79626240 | ob 26542080
    char* ws = (char*)d_ws;
    short* Wb  = (short*)(ws);
    short* Wpb = (short*)(ws + 221184);
    short* qb  = (short*)(ws + 294912);
    short* kb  = (short*)(ws + 294912 + 26542080);
    short* vtb = (short*)(ws + 294912 + 26542080 + 79626240);
    short* ob  = (short*)(ws + 294912 + 26542080 + 79626240 + 79626240);
    // total: 212,631,552 bytes (unchanged)

    hipLaunchKernelGGL(kW, dim3(576), dim3(256), 0, stream, w_qkv, w_proj, Wb, Wpb);
    hipLaunchKernelGGL(kA, dim3(3456), dim3(256), 0, stream, x, Wb, b_qkv, shiftp, qb, kb, vtb, pred_q);
    hipLaunchKernelGGL(kB, dim3(NWIN * 6), dim3(256), 0, stream, qb, kb, vtb, rpb, ob);
    hipLaunchKernelGGL(kC, dim3(NWIN), dim3(256), 0, stream, ob, Wpb, b_proj, shiftp, xo, x_pred);
}